// Round 15
// baseline (850.173 us; speedup 1.0000x reference)
//
#include <hip/hip_runtime.h>
#include <hip/hip_bf16.h>

typedef __attribute__((ext_vector_type(8))) short short8;
typedef __attribute__((ext_vector_type(4))) float f32x4;
typedef unsigned int uint32;

#define GLD16(g, l) __builtin_amdgcn_global_load_lds( \
    (const __attribute__((address_space(1))) unsigned int*)(g), \
    (__attribute__((address_space(3))) unsigned int*)(l), 16, 0, 0)

__device__ __forceinline__ float bfu(unsigned short u) {
    union { uint32 v; float f; } x; x.v = ((uint32)u) << 16; return x.f;
}
__device__ __forceinline__ void storev(float* p, float v) { *p = v; }
__device__ __forceinline__ void storev(__hip_bfloat16* p, float v) { *p = __float2bfloat16(v); }

// ============ transpose fp32 [K,N] -> bf16 [N,K] ============
__global__ __launch_bounds__(256) void transpose_bf16(
    const float* __restrict__ W, __hip_bfloat16* __restrict__ WT, int K, int N)
{
    __shared__ float tile[32][33];
    int k0 = blockIdx.x * 32, n0 = blockIdx.y * 32;
    int tx = threadIdx.x & 31, ty = threadIdx.x >> 5;   // 32 x 8
    #pragma unroll
    for (int i = 0; i < 32; i += 8)
        tile[ty + i][tx] = W[(size_t)(k0 + ty + i) * N + n0 + tx];
    __syncthreads();
    #pragma unroll
    for (int i = 0; i < 32; i += 8)
        WT[(size_t)(n0 + ty + i) * K + k0 + tx] = __float2bfloat16(tile[tx][ty + i]);
}

__global__ __launch_bounds__(256) void cast_bf16(
    const float* __restrict__ W, __hip_bfloat16* __restrict__ O, int total)
{
    int idx = blockIdx.x * 256 + threadIdx.x;
    if (idx < total) O[idx] = __float2bfloat16(W[idx]);
}

// ============ encoders ============
__global__ __launch_bounds__(256) void encode_nodes(
    const float* __restrict__ x, const float* __restrict__ Wn,
    const float* __restrict__ bn, __hip_bfloat16* __restrict__ h, int Nn)
{
    int idx = blockIdx.x * 256 + threadIdx.x;
    if (idx >= Nn * 512) return;
    int n = idx >> 9, c = idx & 511;
    float acc = bn[c];
    #pragma unroll
    for (int f = 0; f < 7; ++f) acc += x[n * 7 + f] * Wn[f * 512 + c];
    h[idx] = __float2bfloat16(fmaxf(acc, 0.f));
}

__global__ __launch_bounds__(256) void encode_edges_sorted(
    const float* __restrict__ eat, const int* __restrict__ elist,
    const float* __restrict__ We, const float* __restrict__ be,
    __hip_bfloat16* __restrict__ ea, int E)
{
    int idx = blockIdx.x * 256 + threadIdx.x;
    if (idx >= E * 512) return;
    int p = idx >> 9, c = idx & 511;
    int e = elist[p];
    float v = fmaf(eat[e * 2], We[c], fmaf(eat[e * 2 + 1], We[512 + c], be[c]));
    ea[idx] = __float2bfloat16(fmaxf(v, 0.f));
}

// ============ bf16 MFMA GEMM, BK=64 ============
template <typename OutT, bool HAS_BIAS>
__global__ __launch_bounds__(256) void mfma_gemm(
    const __hip_bfloat16* __restrict__ A, int lda, long az,
    const __hip_bfloat16* __restrict__ BT, int ldb, long bz,
    const float* __restrict__ bias, long biasz,
    OutT* __restrict__ C, int ldc, long cz, int M, int K)
{
    __shared__ uint4 As4[1024];   // 16 KB
    __shared__ uint4 Bs4[1024];
    A  += (long)blockIdx.z * az;
    BT += (long)blockIdx.z * bz;
    C  += (long)blockIdx.z * cz;
    if (HAS_BIAS) bias += (long)blockIdx.z * biasz;
    const int t = threadIdx.x, lane = t & 63, w = t >> 6;
    const int wr = (w >> 1) * 64, wc = (w & 1) * 64;
    const int col0 = blockIdx.x * 128, row0 = blockIdx.y * 128;  // x = col tile (fast)
    const int lr = lane & 15, lg = lane >> 4;
    const int srow8 = lane >> 3;
    const int sch   = (lane & 7) ^ srow8;
    const int rx = lr & 7;

    const __hip_bfloat16* ApL = A + (size_t)(row0 + srow8) * lda + sch * 8;
    const __hip_bfloat16* BpL = BT + (size_t)(col0 + srow8) * ldb + sch * 8;

    f32x4 acc[4][4];
    #pragma unroll
    for (int m = 0; m < 4; ++m)
        #pragma unroll
        for (int n = 0; n < 4; ++n) acc[m][n] = 0.f;

    for (int k0 = 0; k0 < K; k0 += 64) {
        #pragma unroll
        for (int j = 0; j < 4; ++j) {
            int rb = (w + 4 * j) * 8;
            GLD16(ApL + (size_t)rb * lda + k0, As4 + (w + 4 * j) * 64);
            GLD16(BpL + (size_t)rb * ldb + k0, Bs4 + (w + 4 * j) * 64);
        }
        __syncthreads();
        #pragma unroll
        for (int kk = 0; kk < 2; ++kk) {
            short8 af[4], bfrag[4];
            #pragma unroll
            for (int m = 0; m < 4; ++m) {
                int row = wr + m * 16 + lr;
                af[m] = *(const short8*)((const char*)As4 + row * 128 + (((kk * 4 + lg) ^ rx) << 4));
            }
            #pragma unroll
            for (int n = 0; n < 4; ++n) {
                int row = wc + n * 16 + lr;
                bfrag[n] = *(const short8*)((const char*)Bs4 + row * 128 + (((kk * 4 + lg) ^ rx) << 4));
            }
            #pragma unroll
            for (int m = 0; m < 4; ++m)
                #pragma unroll
                for (int n = 0; n < 4; ++n)
                    acc[m][n] = __builtin_amdgcn_mfma_f32_16x16x32_bf16(af[m], bfrag[n], acc[m][n], 0, 0, 0);
        }
        __syncthreads();
    }

    #pragma unroll
    for (int m = 0; m < 4; ++m) {
        #pragma unroll
        for (int r = 0; r < 4; ++r) {
            int gr = row0 + wr + m * 16 + lg * 4 + r;
            if (gr >= M) continue;
            #pragma unroll
            for (int n = 0; n < 4; ++n) {
                int gc = col0 + wc + n * 16 + lr;
                float v = acc[m][n][r];
                if (HAS_BIAS) v += bias[gc];
                storev(&C[(size_t)gr * ldc + gc], v);
            }
        }
    }
}

// ============ edge GEMM (BK=64) + fused logits, sorted-edge space ============
// Epilogue: single-phase full 128-col XL/XR block, 256B/row gathers, XOR-swizzled.
__global__ __launch_bounds__(256) void edge_mfma_logits(
    const __hip_bfloat16* __restrict__ ea,
    const __hip_bfloat16* __restrict__ WleT,
    const __hip_bfloat16* __restrict__ XL,
    const __hip_bfloat16* __restrict__ XR,
    const int* __restrict__ ssrc,
    const int* __restrict__ sdst,
    const float* __restrict__ att,
    float* __restrict__ logits,
    int E)
{
    __shared__ uint4 As4[2048];   // 32 KB: K-loop uses [0,1024); strips use all
    __shared__ uint4 Bs4[2048];
    __shared__ int srcs[128], dsts[128];
    const int t = threadIdx.x, lane = t & 63, w = t >> 6;
    const int wr = (w >> 1) * 64, wc = (w & 1) * 64;
    const int col0 = blockIdx.x * 128, row0 = blockIdx.y * 128;
    const int lr = lane & 15, lg = lane >> 4;
    const int srow8 = lane >> 3;
    const int sch   = (lane & 7) ^ srow8;
    const int rx = lr & 7;

    if (t < 128) {
        int ge = row0 + t;
        bool ok = ge < E;
        srcs[t] = ok ? ssrc[ge] : 0;
        dsts[t] = ok ? sdst[ge] : 0;
    }
    const __hip_bfloat16* ApL = ea + (size_t)(row0 + srow8) * 512 + sch * 8;
    const __hip_bfloat16* BpL = WleT + (size_t)(col0 + srow8) * 512 + sch * 8;
    __syncthreads();

    f32x4 acc[4][4];
    #pragma unroll
    for (int m = 0; m < 4; ++m)
        #pragma unroll
        for (int n = 0; n < 4; ++n) acc[m][n] = 0.f;

    for (int k0 = 0; k0 < 512; k0 += 64) {
        #pragma unroll
        for (int j = 0; j < 4; ++j) {
            int rb = (w + 4 * j) * 8;
            GLD16(ApL + (size_t)rb * 512 + k0, As4 + (w + 4 * j) * 64);
            GLD16(BpL + (size_t)rb * 512 + k0, Bs4 + (w + 4 * j) * 64);
        }
        __syncthreads();
        #pragma unroll
        for (int kk = 0; kk < 2; ++kk) {
            short8 af[4], bfrag[4];
            #pragma unroll
            for (int m = 0; m < 4; ++m) {
                int row = wr + m * 16 + lr;
                af[m] = *(const short8*)((const char*)As4 + row * 128 + (((kk * 4 + lg) ^ rx) << 4));
            }
            #pragma unroll
            for (int n = 0; n < 4; ++n) {
                int row = wc + n * 16 + lr;
                bfrag[n] = *(const short8*)((const char*)Bs4 + row * 128 + (((kk * 4 + lg) ^ rx) << 4));
            }
            #pragma unroll
            for (int m = 0; m < 4; ++m)
                #pragma unroll
                for (int n = 0; n < 4; ++n)
                    acc[m][n] = __builtin_amdgcn_mfma_f32_16x16x32_bf16(af[m], bfrag[n], acc[m][n], 0, 0, 0);
        }
        __syncthreads();
    }

    // ---- logits epilogue: stage XL/XR [128 rows x 128 cols] once ----
    // LDS layout per operand: row*256B + slot*16B, slot = chunk ^ (row&7)
    const int hh = col0 >> 9;
    float attv[4];
    #pragma unroll
    for (int n = 0; n < 4; ++n)
        attv[n] = att[hh * 512 + ((col0 + wc + n * 16 + lr) & 511)];

    {
        const int rsub = lane >> 4;            // row within 4-row group
        const int schunk = (lane & 15);        // LDS 16B slot
        #pragma unroll
        for (int j = 0; j < 8; ++j) {
            int rowg = w + 4 * j;              // 0..31
            int row = rowg * 4 + rsub;
            int gch = schunk ^ (row & 7);      // global chunk pre-swizzled
            GLD16(XL + (size_t)srcs[row] * 2048 + col0 + gch * 8, As4 + rowg * 64);
            GLD16(XR + (size_t)dsts[row] * 2048 + col0 + gch * 8, Bs4 + rowg * 64);
        }
    }
    __syncthreads();

    float part[4][4];
    #pragma unroll
    for (int m = 0; m < 4; ++m)
        #pragma unroll
        for (int r = 0; r < 4; ++r) part[m][r] = 0.f;

    #pragma unroll
    for (int n = 0; n < 4; ++n) {
        int ecol = wc + n * 16 + lr;           // 0..127 within tile
        #pragma unroll
        for (int m = 0; m < 4; ++m) {
            #pragma unroll
            for (int r = 0; r < 4; ++r) {
                int row = wr + m * 16 + lg * 4 + r;
                int slot = (ecol >> 3) ^ (row & 7);
                int off = row * 256 + slot * 16 + (ecol & 7) * 2;
                float xl = bfu(*(const unsigned short*)((const char*)As4 + off));
                float xr = bfu(*(const unsigned short*)((const char*)Bs4 + off));
                float mv = acc[m][n][r] + xl + xr;
                part[m][r] += attv[n] * ((mv > 0.f) ? mv : 0.2f * mv);
            }
        }
    }
    #pragma unroll
    for (int m = 0; m < 4; ++m) {
        #pragma unroll
        for (int r = 0; r < 4; ++r) {
            float p = part[m][r];
            p += __shfl_xor(p, 1); p += __shfl_xor(p, 2);
            p += __shfl_xor(p, 4); p += __shfl_xor(p, 8);
            int ge = row0 + wr + m * 16 + lg * 4 + r;
            if (lr == 0 && ge < E) atomicAdd(&logits[ge * 4 + hh], p);
        }
    }
}

// ============ counting sort ============
__global__ __launch_bounds__(256) void count_dst(
    const int* __restrict__ ei, int* __restrict__ cnt, int E)
{
    int e = blockIdx.x * 256 + threadIdx.x;
    if (e < E) atomicAdd(&cnt[ei[E + e]], 1);
}

__global__ __launch_bounds__(1024) void scan_kernel(
    const int* __restrict__ cnt, int* __restrict__ offs, int N)
{
    __shared__ int wsum[16];
    __shared__ int stot;
    __shared__ int carry_s;
    int t = threadIdx.x, lane = t & 63, w = t >> 6;
    if (t == 0) carry_s = 0;
    __syncthreads();
    for (int base = 0; base < N; base += 1024) {
        int v = (base + t < N) ? cnt[base + t] : 0;
        int x = v;
        #pragma unroll
        for (int off = 1; off < 64; off <<= 1) {
            int y = __shfl_up(x, off);
            if (lane >= off) x += y;
        }
        if (lane == 63) wsum[w] = x;
        __syncthreads();
        if (w == 0 && lane < 16) {
            int v0 = wsum[lane];
            int s = v0;
            #pragma unroll
            for (int off = 1; off < 16; off <<= 1) {
                int y = __shfl_up(s, off);
                if (lane >= off) s += y;
            }
            wsum[lane] = s - v0;
            if (lane == 15) stot = s;
        }
        __syncthreads();
        if (base + t < N) offs[base + t] = carry_s + wsum[w] + x - v;
        __syncthreads();
        if (t == 0) carry_s += stot;
    }
    __syncthreads();
    if (t == 0) offs[N] = carry_s;
}

__global__ __launch_bounds__(256) void fill_elist(
    const int* __restrict__ ei, const int* __restrict__ offs,
    int* __restrict__ cnt2, int* __restrict__ elist,
    int* __restrict__ ssrc, int* __restrict__ sdst, int E)
{
    int e = blockIdx.x * 256 + threadIdx.x;
    if (e >= E) return;
    int d = ei[E + e];
    int p = offs[d] + atomicAdd(&cnt2[d], 1);
    elist[p] = e;
    ssrc[p] = ei[e];
    sdst[p] = d;
}

// ============ bias prep ============
__global__ __launch_bounds__(256) void bias_init(
    const float* __restrict__ bd1, float* __restrict__ bias2, float* __restrict__ blw)
{
    int j = blockIdx.x * 256 + threadIdx.x;
    if (j < 512) { bias2[j] = bd1[j]; blw[j] = 0.f; }
}
__global__ __launch_bounds__(256) void bias_acc(
    const float* __restrict__ cb, const float* __restrict__ bl,
    const float* __restrict__ Wd1, float* __restrict__ bias2, float* __restrict__ blw)
{
    int g = blockIdx.x * 256 + threadIdx.x;   // 8192 threads: 512 j x 16 slices
    int j = g & 511, slice = g >> 9;
    float pa = 0.f, pb = 0.f;
    for (int k = slice * 128; k < slice * 128 + 128; ++k) {
        float wv = Wd1[(size_t)k * 512 + j];
        pa += cb[k] * wv;
        pb += bl[k] * wv;
    }
    atomicAdd(&bias2[j], pa);
    atomicAdd(&blw[j], pb);
}

// ============ fused output ============
__global__ __launch_bounds__(256) void gat_out(
    const __hip_bfloat16* __restrict__ Y,     // [N,4,512] bf16 (no bias terms)
    const int* __restrict__ ssrc, const int* __restrict__ offs,
    const float* __restrict__ logits,         // [E,4] sorted
    const float* __restrict__ bias2, const float* __restrict__ blw,
    const float* __restrict__ Wd2,
    const float* __restrict__ bd2,
    float* __restrict__ out, int N)
{
    __shared__ float wds[512 * 6];
    int t = threadIdx.x;
    for (int i = t; i < 512 * 6; i += 256) wds[i] = Wd2[i];
    __syncthreads();
    int w = t >> 6, lane = t & 63;
    int dst = blockIdx.x * 4 + w;
    if (dst >= N) return;
    int s = offs[dst], cntE = offs[dst + 1] - s;

    float den[4] = {0.f, 0.f, 0.f, 0.f};
    for (int i = 0; i < cntE; ++i) {
        #pragma unroll
        for (int h = 0; h < 4; ++h) den[h] += expf(logits[(s + i) * 4 + h]);
    }
    float acc[8] = {0.f, 0.f, 0.f, 0.f, 0.f, 0.f, 0.f, 0.f};
    for (int i = 0; i < cntE; ++i) {
        int p = s + i;
        int src = ssrc[p];
        #pragma unroll
        for (int h = 0; h < 4; ++h) {
            float al = expf(logits[p * 4 + h]) / (den[h] + 1e-16f);
            uint4 q = *(const uint4*)((const unsigned short*)Y
                        + ((size_t)src * 4 + h) * 512 + lane * 8);
            acc[0] += al * bfu((unsigned short)(q.x & 0xffff));
            acc[1] += al * bfu((unsigned short)(q.x >> 16));
            acc[2] += al * bfu((unsigned short)(q.y & 0xffff));
            acc[3] += al * bfu((unsigned short)(q.y >> 16));
            acc[4] += al * bfu((unsigned short)(q.z & 0xffff));
            acc[5] += al * bfu((unsigned short)(q.z >> 16));
            acc[6] += al * bfu((unsigned short)(q.w & 0xffff));
            acc[7] += al * bfu((unsigned short)(q.w >> 16));
        }
    }
    float gate = (cntE > 0) ? 1.f : 0.f;
    float p6[6] = {0.f, 0.f, 0.f, 0.f, 0.f, 0.f};
    #pragma unroll
    for (int j = 0; j < 8; ++j) {
        int c = lane * 8 + j;
        float u = fmaxf(acc[j] + bias2[c] + gate * blw[c], 0.f);
        #pragma unroll
        for (int jj = 0; jj < 6; ++jj) p6[jj] += u * wds[c * 6 + jj];
    }
    #pragma unroll
    for (int off = 32; off; off >>= 1)
        #pragma unroll
        for (int jj = 0; jj < 6; ++jj) p6[jj] += __shfl_down(p6[jj], off);
    if (lane == 0) {
        #pragma unroll
        for (int jj = 0; jj < 6; ++jj)
            out[(size_t)dst * 6 + jj] = 1.f / (1.f + expf(-(p6[jj] + bd2[jj])));
    }
}

extern "C" void kernel_launch(void* const* d_in, const int* in_sizes, int n_in,
                              void* d_out, int out_size, void* d_ws, size_t ws_size,
                              hipStream_t stream)
{
    const float* x         = (const float*)d_in[0];
    const float* edge_attr = (const float*)d_in[1];
    const int*   ei        = (const int*)d_in[2];
    const float* W_node = (const float*)d_in[3],  *b_node = (const float*)d_in[4];
    const float* W_edge = (const float*)d_in[5],  *b_edge = (const float*)d_in[6];
    const float* W_l    = (const float*)d_in[7],  *b_l    = (const float*)d_in[8];
    const float* W_r    = (const float*)d_in[9],  *b_r    = (const float*)d_in[10];
    const float* W_le   = (const float*)d_in[11];
    const float* att    = (const float*)d_in[12];
    const float* conv_bias = (const float*)d_in[13];
    const float* W_d1   = (const float*)d_in[14], *b_d1 = (const float*)d_in[15];
    const float* W_d2   = (const float*)d_in[16], *b_d2 = (const float*)d_in[17];
    float* out = (float*)d_out;

    const int N = in_sizes[0] / 7;   // 25000
    const int E = in_sizes[1] / 2;   // 50000
    const int MP = (N + 127) & ~127;
    const int EP = (E + 127) & ~127;

    // ---- workspace layout (~268 MB, same as round 12) ----
    char* ws = (char*)d_ws;
    const size_t szR0 = (size_t)EP * 512 * 2;
    const size_t szX  = (size_t)MP * 2048 * 2;
    const size_t szW  = (size_t)2048 * 512 * 2;   // 2 MB
    const size_t szlg = (size_t)E * 4 * 4;
    const size_t szI  = (((size_t)(N + 1) * 4) + 15) & ~(size_t)15;
    const size_t o_XL = szR0;
    const size_t o_XR = o_XL + szX;
    const size_t o_W  = o_XR + szX;                // WlT, WrT, WleT, WcombT
    const size_t o_lg = o_W + 4 * szW;
    const size_t o_b2 = o_lg + szlg;
    const size_t o_blw = o_b2 + 2048;
    const size_t o_bc = o_blw + 2048;
    const size_t o_cnt = o_bc + 4096 * 4;
    const size_t o_cnt2 = o_cnt + szI;
    const size_t o_off = o_cnt2 + szI;
    const size_t o_el = o_off + szI;
    const size_t o_ss = o_el + (size_t)E * 4;
    const size_t o_sd = o_ss + (size_t)E * 4;
    const size_t need = o_sd + (size_t)E * 4;
    if (ws_size < need) return;   // clean diagnostic failure if ws too small

    __hip_bfloat16* h   = (__hip_bfloat16*)ws;      // region0
    __hip_bfloat16* ea  = (__hip_bfloat16*)ws;      // region0 (overlays h)
    __hip_bfloat16* XL  = (__hip_bfloat16*)(ws + o_XL);
    __hip_bfloat16* XR  = (__hip_bfloat16*)(ws + o_XR);
    __hip_bfloat16* Y   = XR;                       // overlays XR after logits
    __hip_bfloat16* WlT = (__hip_bfloat16*)(ws + o_W);
    __hip_bfloat16* WrT = WlT + szW / 2;
    __hip_bfloat16* WleT= WrT + szW / 2;
    __hip_bfloat16* WcombT = WleT + szW / 2;        // [2048,512]
    __hip_bfloat16* Wd1T_t = (__hip_bfloat16*)(ws + o_XL);           // transient
    __hip_bfloat16* Wlbf_t = (__hip_bfloat16*)(ws + o_XL + szW);     // transient
    float* logits = (float*)(ws + o_lg);
    float* bias2  = (float*)(ws + o_b2);
    float* blw    = (float*)(ws + o_blw);
    float* bcat   = (float*)(ws + o_bc);
    int* cnt   = (int*)(ws + o_cnt);
    int* cnt2  = (int*)(ws + o_cnt2);
    int* offs  = (int*)(ws + o_off);
    int* elist = (int*)(ws + o_el);
    int* ssrc  = (int*)(ws + o_ss);
    int* sdst  = (int*)(ws + o_sd);

    hipMemsetAsync(logits, 0, szlg, stream);
    hipMemsetAsync(cnt, 0, szI, stream);
    hipMemsetAsync(cnt2, 0, szI, stream);
    hipMemcpyAsync(bcat, b_l, 2048 * 4, hipMemcpyDeviceToDevice, stream);
    hipMemcpyAsync(bcat + 2048, b_r, 2048 * 4, hipMemcpyDeviceToDevice, stream);

    // ---- weight prep ----
    dim3 gT(512 / 32, 2048 / 32);
    transpose_bf16<<<gT, 256, 0, stream>>>(W_l,  WlT, 512, 2048);
    transpose_bf16<<<gT, 256, 0, stream>>>(W_r,  WrT, 512, 2048);
    transpose_bf16<<<gT, 256, 0, stream>>>(W_le, WleT, 512, 2048);
    dim3 gT2(2048 / 32, 512 / 32);
    transpose_bf16<<<gT2, 256, 0, stream>>>(W_d1, Wd1T_t, 2048, 512);
    cast_bf16<<<(512 * 2048 + 255) / 256, 256, 0, stream>>>(W_l, Wlbf_t, 512 * 2048);

    // WcombT[hz*512+j, k] = sum_c W_d1[hz*512+c, j] * W_l[k, hz*512+c]
    dim3 gWc(512 / 128, 512 / 128, 4);
    mfma_gemm<__hip_bfloat16, false><<<gWc, 256, 0, stream>>>(
        Wd1T_t, 2048, 512, Wlbf_t, 2048, 512, nullptr, 0,
        WcombT, 512, (long)512 * 512, 512, 512);

    bias_init<<<2, 256, 0, stream>>>(b_d1, bias2, blw);
    bias_acc<<<32, 256, 0, stream>>>(conv_bias, b_l, W_d1, bias2, blw);

    // ---- counting sort of edges by dst ----
    count_dst<<<(E + 255) / 256, 256, 0, stream>>>(ei, cnt, E);
    scan_kernel<<<1, 1024, 0, stream>>>(cnt, offs, N);
    fill_elist<<<(E + 255) / 256, 256, 0, stream>>>(ei, offs, cnt2, elist, ssrc, sdst, E);

    // ---- h(1) -> XL/XR ----
    encode_nodes<<<(N * 512 + 255) / 256, 256, 0, stream>>>(x, W_node, b_node, h, N);

    const int MB = MP / 128;
    dim3 gNode(2048 / 128, MB, 2);
    mfma_gemm<__hip_bfloat16, true><<<gNode, 256, 0, stream>>>(
        h, 512, 0, WlT, 512, (long)2048 * 512, bcat, 2048,
        XL, 2048, (long)MP * 2048, N, 512);

    // ---- ea (overlays h) -> edge logits ----
    encode_edges_sorted<<<(E * 512 + 255) / 256, 256, 0, stream>>>(
        edge_attr, elist, W_edge, b_edge, ea, E);

    dim3 gE(16, EP / 128);
    edge_mfma_logits<<<gE, 256, 0, stream>>>(ea, WleT, XL, XR, ssrc, sdst, att, logits, E);

    // ---- h(2) (overlays ea) -> Y = h @ WcombT (Y overlays dead XR) ----
    encode_nodes<<<(N * 512 + 255) / 256, 256, 0, stream>>>(x, W_node, b_node, h, N);

    dim3 gY(2048 / 128, MB);
    mfma_gemm<__hip_bfloat16, false><<<gY, 256, 0, stream>>>(
        h, 512, 0, WcombT, 512, 0, nullptr, 0, Y, 2048, 0, N, 512);

    gat_out<<<(N + 3) / 4, 256, 0, stream>>>(Y, ssrc, offs, logits,
                                             bias2, blw, W_d2, b_d2, out, N);
}

// Round 16
// 828.738 us; speedup vs baseline: 1.0259x; 1.0259x over previous
//
#include <hip/hip_runtime.h>
#include <hip/hip_bf16.h>

typedef __attribute__((ext_vector_type(8))) short short8;
typedef __attribute__((ext_vector_type(4))) float f32x4;
typedef unsigned int uint32;

#define GLD16(g, l) __builtin_amdgcn_global_load_lds( \
    (const __attribute__((address_space(1))) unsigned int*)(g), \
    (__attribute__((address_space(3))) unsigned int*)(l), 16, 0, 0)

__device__ __forceinline__ float bfu(unsigned short u) {
    union { uint32 v; float f; } x; x.v = ((uint32)u) << 16; return x.f;
}
__device__ __forceinline__ void storev(float* p, float v) { *p = v; }
__device__ __forceinline__ void storev(__hip_bfloat16* p, float v) { *p = __float2bfloat16(v); }

// ============ transpose fp32 [K,N] -> bf16 [N,K] ============
__global__ __launch_bounds__(256) void transpose_bf16(
    const float* __restrict__ W, __hip_bfloat16* __restrict__ WT, int K, int N)
{
    __shared__ float tile[32][33];
    int k0 = blockIdx.x * 32, n0 = blockIdx.y * 32;
    int tx = threadIdx.x & 31, ty = threadIdx.x >> 5;   // 32 x 8
    #pragma unroll
    for (int i = 0; i < 32; i += 8)
        tile[ty + i][tx] = W[(size_t)(k0 + ty + i) * N + n0 + tx];
    __syncthreads();
    #pragma unroll
    for (int i = 0; i < 32; i += 8)
        WT[(size_t)(n0 + ty + i) * K + k0 + tx] = __float2bfloat16(tile[tx][ty + i]);
}

__global__ __launch_bounds__(256) void cast_bf16(
    const float* __restrict__ W, __hip_bfloat16* __restrict__ O, int total)
{
    int idx = blockIdx.x * 256 + threadIdx.x;
    if (idx < total) O[idx] = __float2bfloat16(W[idx]);
}

// ============ encoders ============
__global__ __launch_bounds__(256) void encode_nodes(
    const float* __restrict__ x, const float* __restrict__ Wn,
    const float* __restrict__ bn, __hip_bfloat16* __restrict__ h, int Nn)
{
    int idx = blockIdx.x * 256 + threadIdx.x;
    if (idx >= Nn * 512) return;
    int n = idx >> 9, c = idx & 511;
    float acc = bn[c];
    #pragma unroll
    for (int f = 0; f < 7; ++f) acc += x[n * 7 + f] * Wn[f * 512 + c];
    h[idx] = __float2bfloat16(fmaxf(acc, 0.f));
}

__global__ __launch_bounds__(256) void encode_edges_sorted(
    const float* __restrict__ eat, const int* __restrict__ elist,
    const float* __restrict__ We, const float* __restrict__ be,
    __hip_bfloat16* __restrict__ ea, int E)
{
    int idx = blockIdx.x * 256 + threadIdx.x;
    if (idx >= E * 512) return;
    int p = idx >> 9, c = idx & 511;
    int e = elist[p];
    float v = fmaf(eat[e * 2], We[c], fmaf(eat[e * 2 + 1], We[512 + c], be[c]));
    ea[idx] = __float2bfloat16(fmaxf(v, 0.f));
}

// ============ bf16 MFMA GEMM, BK=64 ============
template <typename OutT, bool HAS_BIAS>
__global__ __launch_bounds__(256) void mfma_gemm(
    const __hip_bfloat16* __restrict__ A, int lda, long az,
    const __hip_bfloat16* __restrict__ BT, int ldb, long bz,
    const float* __restrict__ bias, long biasz,
    OutT* __restrict__ C, int ldc, long cz, int M, int K)
{
    __shared__ uint4 As4[1024];   // 16 KB
    __shared__ uint4 Bs4[1024];
    A  += (long)blockIdx.z * az;
    BT += (long)blockIdx.z * bz;
    C  += (long)blockIdx.z * cz;
    if (HAS_BIAS) bias += (long)blockIdx.z * biasz;
    const int t = threadIdx.x, lane = t & 63, w = t >> 6;
    const int wr = (w >> 1) * 64, wc = (w & 1) * 64;
    const int col0 = blockIdx.x * 128, row0 = blockIdx.y * 128;  // x = col tile (fast)
    const int lr = lane & 15, lg = lane >> 4;
    const int srow8 = lane >> 3;
    const int sch   = (lane & 7) ^ srow8;
    const int rx = lr & 7;

    const __hip_bfloat16* ApL = A + (size_t)(row0 + srow8) * lda + sch * 8;
    const __hip_bfloat16* BpL = BT + (size_t)(col0 + srow8) * ldb + sch * 8;

    f32x4 acc[4][4];
    #pragma unroll
    for (int m = 0; m < 4; ++m)
        #pragma unroll
        for (int n = 0; n < 4; ++n) acc[m][n] = 0.f;

    for (int k0 = 0; k0 < K; k0 += 64) {
        #pragma unroll
        for (int j = 0; j < 4; ++j) {
            int rb = (w + 4 * j) * 8;
            GLD16(ApL + (size_t)rb * lda + k0, As4 + (w + 4 * j) * 64);
            GLD16(BpL + (size_t)rb * ldb + k0, Bs4 + (w + 4 * j) * 64);
        }
        __syncthreads();
        #pragma unroll
        for (int kk = 0; kk < 2; ++kk) {
            short8 af[4], bfrag[4];
            #pragma unroll
            for (int m = 0; m < 4; ++m) {
                int row = wr + m * 16 + lr;
                af[m] = *(const short8*)((const char*)As4 + row * 128 + (((kk * 4 + lg) ^ rx) << 4));
            }
            #pragma unroll
            for (int n = 0; n < 4; ++n) {
                int row = wc + n * 16 + lr;
                bfrag[n] = *(const short8*)((const char*)Bs4 + row * 128 + (((kk * 4 + lg) ^ rx) << 4));
            }
            #pragma unroll
            for (int m = 0; m < 4; ++m)
                #pragma unroll
                for (int n = 0; n < 4; ++n)
                    acc[m][n] = __builtin_amdgcn_mfma_f32_16x16x32_bf16(af[m], bfrag[n], acc[m][n], 0, 0, 0);
        }
        __syncthreads();
    }

    #pragma unroll
    for (int m = 0; m < 4; ++m) {
        #pragma unroll
        for (int r = 0; r < 4; ++r) {
            int gr = row0 + wr + m * 16 + lg * 4 + r;
            if (gr >= M) continue;
            #pragma unroll
            for (int n = 0; n < 4; ++n) {
                int gc = col0 + wc + n * 16 + lr;
                float v = acc[m][n][r];
                if (HAS_BIAS) v += bias[gc];
                storev(&C[(size_t)gr * ldc + gc], v);
            }
        }
    }
}

// ============ edge GEMM (BK=64) + fused logits; 1D grid + XCD swizzle ============
__global__ __launch_bounds__(256) void edge_mfma_logits(
    const __hip_bfloat16* __restrict__ ea,
    const __hip_bfloat16* __restrict__ WleT,
    const __hip_bfloat16* __restrict__ XL,
    const __hip_bfloat16* __restrict__ XR,
    const int* __restrict__ ssrc,
    const int* __restrict__ sdst,
    const float* __restrict__ att,
    float* __restrict__ logits,
    int E)
{
    __shared__ uint4 As4[1024];
    __shared__ uint4 Bs4[1024];
    __shared__ int srcs[128], dsts[128];
    const int t = threadIdx.x, lane = t & 63, w = t >> 6;
    const int wr = (w >> 1) * 64, wc = (w & 1) * 64;
    // XCD-aware chunked swizzle (bijective since gridDim.x % 8 == 0); each XCD
    // gets a contiguous run of the col-fast sequence -> ea/src/dst rows L2-hit.
    int lid = ((gridDim.x & 7) == 0)
              ? ((blockIdx.x & 7) * (gridDim.x >> 3) + (blockIdx.x >> 3))
              : blockIdx.x;
    const int col0 = (lid & 15) * 128;
    const int row0 = (lid >> 4) * 128;
    const int lr = lane & 15, lg = lane >> 4;
    const int srow8 = lane >> 3;
    const int sch   = (lane & 7) ^ srow8;
    const int rx = lr & 7;

    if (t < 128) {
        int ge = row0 + t;
        bool ok = ge < E;
        srcs[t] = ok ? ssrc[ge] : 0;
        dsts[t] = ok ? sdst[ge] : 0;
    }
    const __hip_bfloat16* ApL = ea + (size_t)(row0 + srow8) * 512 + sch * 8;
    const __hip_bfloat16* BpL = WleT + (size_t)(col0 + srow8) * 512 + sch * 8;
    __syncthreads();

    f32x4 acc[4][4];
    #pragma unroll
    for (int m = 0; m < 4; ++m)
        #pragma unroll
        for (int n = 0; n < 4; ++n) acc[m][n] = 0.f;

    for (int k0 = 0; k0 < 512; k0 += 64) {
        #pragma unroll
        for (int j = 0; j < 4; ++j) {
            int rb = (w + 4 * j) * 8;
            GLD16(ApL + (size_t)rb * 512 + k0, As4 + (w + 4 * j) * 64);
            GLD16(BpL + (size_t)rb * 512 + k0, Bs4 + (w + 4 * j) * 64);
        }
        __syncthreads();
        #pragma unroll
        for (int kk = 0; kk < 2; ++kk) {
            short8 af[4], bfrag[4];
            #pragma unroll
            for (int m = 0; m < 4; ++m) {
                int row = wr + m * 16 + lr;
                af[m] = *(const short8*)((const char*)As4 + row * 128 + (((kk * 4 + lg) ^ rx) << 4));
            }
            #pragma unroll
            for (int n = 0; n < 4; ++n) {
                int row = wc + n * 16 + lr;
                bfrag[n] = *(const short8*)((const char*)Bs4 + row * 128 + (((kk * 4 + lg) ^ rx) << 4));
            }
            #pragma unroll
            for (int m = 0; m < 4; ++m)
                #pragma unroll
                for (int n = 0; n < 4; ++n)
                    acc[m][n] = __builtin_amdgcn_mfma_f32_16x16x32_bf16(af[m], bfrag[n], acc[m][n], 0, 0, 0);
        }
        __syncthreads();
    }

    // ---- logits epilogue: XL/XR 32-col strips; 2 strips per drain, balanced ----
    const int hh = col0 >> 9;
    float attv[4];
    #pragma unroll
    for (int n = 0; n < 4; ++n)
        attv[n] = att[hh * 512 + ((col0 + wc + n * 16 + lr) & 511)];
    float part[4][4];
    #pragma unroll
    for (int m = 0; m < 4; ++m)
        #pragma unroll
        for (int r = 0; r < 4; ++r) part[m][r] = 0.f;

    const int prt = (lane & 3) * 8;
    const int r0e = w * 16 + (lane >> 2);
    const int s0 = srcs[r0e], s1 = srcs[r0e + 64];
    const int d0 = dsts[r0e], d1 = dsts[r0e + 64];

    #pragma unroll
    for (int pair = 0; pair < 2; ++pair) {
        #pragma unroll
        for (int sp = 0; sp < 2; ++sp) {
            int ch = pair + sp * 2;
            int cc = col0 + ch * 32;
            GLD16(XL + (size_t)s0 * 2048 + cc + prt, As4 + sp * 512 + w * 64);
            GLD16(XL + (size_t)s1 * 2048 + cc + prt, As4 + sp * 512 + (w + 4) * 64);
            GLD16(XR + (size_t)d0 * 2048 + cc + prt, Bs4 + sp * 512 + w * 64);
            GLD16(XR + (size_t)d1 * 2048 + cc + prt, Bs4 + sp * 512 + (w + 4) * 64);
        }
        __syncthreads();
        #pragma unroll
        for (int sp = 0; sp < 2; ++sp) {
            int ch = pair + sp * 2;
            const char* AsB = (const char*)(As4 + sp * 512);
            const char* BsB = (const char*)(Bs4 + sp * 512);
            #pragma unroll
            for (int n = 0; n < 4; ++n) {
                if (((wc + n * 16) >> 5) != ch) continue;
                int colin = ((n & 1) << 4) + lr;
                #pragma unroll
                for (int m = 0; m < 4; ++m) {
                    #pragma unroll
                    for (int r = 0; r < 4; ++r) {
                        int row = wr + m * 16 + lg * 4 + r;
                        float xl = bfu(*(const unsigned short*)(AsB + row * 64 + colin * 2));
                        float xr = bfu(*(const unsigned short*)(BsB + row * 64 + colin * 2));
                        float mv = acc[m][n][r] + xl + xr;
                        part[m][r] += attv[n] * ((mv > 0.f) ? mv : 0.2f * mv);
                    }
                }
            }
        }
        __syncthreads();
    }
    #pragma unroll
    for (int m = 0; m < 4; ++m) {
        #pragma unroll
        for (int r = 0; r < 4; ++r) {
            float p = part[m][r];
            p += __shfl_xor(p, 1); p += __shfl_xor(p, 2);
            p += __shfl_xor(p, 4); p += __shfl_xor(p, 8);
            int ge = row0 + wr + m * 16 + lg * 4 + r;
            if (lr == 0 && ge < E) atomicAdd(&logits[ge * 4 + hh], p);
        }
    }
}

// ============ counting sort ============
__global__ __launch_bounds__(256) void count_dst(
    const int* __restrict__ ei, int* __restrict__ cnt, int E)
{
    int e = blockIdx.x * 256 + threadIdx.x;
    if (e < E) atomicAdd(&cnt[ei[E + e]], 1);
}

__global__ __launch_bounds__(1024) void scan_kernel(
    const int* __restrict__ cnt, int* __restrict__ offs, int N)
{
    __shared__ int wsum[16];
    __shared__ int stot;
    __shared__ int carry_s;
    int t = threadIdx.x, lane = t & 63, w = t >> 6;
    if (t == 0) carry_s = 0;
    __syncthreads();
    for (int base = 0; base < N; base += 1024) {
        int v = (base + t < N) ? cnt[base + t] : 0;
        int x = v;
        #pragma unroll
        for (int off = 1; off < 64; off <<= 1) {
            int y = __shfl_up(x, off);
            if (lane >= off) x += y;
        }
        if (lane == 63) wsum[w] = x;
        __syncthreads();
        if (w == 0 && lane < 16) {
            int v0 = wsum[lane];
            int s = v0;
            #pragma unroll
            for (int off = 1; off < 16; off <<= 1) {
                int y = __shfl_up(s, off);
                if (lane >= off) s += y;
            }
            wsum[lane] = s - v0;
            if (lane == 15) stot = s;
        }
        __syncthreads();
        if (base + t < N) offs[base + t] = carry_s + wsum[w] + x - v;
        __syncthreads();
        if (t == 0) carry_s += stot;
    }
    __syncthreads();
    if (t == 0) offs[N] = carry_s;
}

__global__ __launch_bounds__(256) void fill_elist(
    const int* __restrict__ ei, const int* __restrict__ offs,
    int* __restrict__ cnt2, int* __restrict__ elist,
    int* __restrict__ ssrc, int* __restrict__ sdst, int E)
{
    int e = blockIdx.x * 256 + threadIdx.x;
    if (e >= E) return;
    int d = ei[E + e];
    int p = offs[d] + atomicAdd(&cnt2[d], 1);
    elist[p] = e;
    ssrc[p] = ei[e];
    sdst[p] = d;
}

// ============ bias prep ============
__global__ __launch_bounds__(256) void bias_init(
    const float* __restrict__ bd1, float* __restrict__ bias2, float* __restrict__ blw)
{
    int j = blockIdx.x * 256 + threadIdx.x;
    if (j < 512) { bias2[j] = bd1[j]; blw[j] = 0.f; }
}
__global__ __launch_bounds__(256) void bias_acc(
    const float* __restrict__ cb, const float* __restrict__ bl,
    const float* __restrict__ Wd1, float* __restrict__ bias2, float* __restrict__ blw)
{
    int g = blockIdx.x * 256 + threadIdx.x;   // 8192 threads: 512 j x 16 slices
    int j = g & 511, slice = g >> 9;
    float pa = 0.f, pb = 0.f;
    for (int k = slice * 128; k < slice * 128 + 128; ++k) {
        float wv = Wd1[(size_t)k * 512 + j];
        pa += cb[k] * wv;
        pb += bl[k] * wv;
    }
    atomicAdd(&bias2[j], pa);
    atomicAdd(&blw[j], pb);
}

// ============ fused output ============
__global__ __launch_bounds__(256) void gat_out(
    const __hip_bfloat16* __restrict__ Y,     // [N,4,512] bf16 (no bias terms)
    const int* __restrict__ ssrc, const int* __restrict__ offs,
    const float* __restrict__ logits,         // [E,4] sorted
    const float* __restrict__ bias2, const float* __restrict__ blw,
    const float* __restrict__ Wd2,
    const float* __restrict__ bd2,
    float* __restrict__ out, int N)
{
    __shared__ float wds[512 * 6];
    int t = threadIdx.x;
    for (int i = t; i < 512 * 6; i += 256) wds[i] = Wd2[i];
    __syncthreads();
    int w = t >> 6, lane = t & 63;
    int dst = blockIdx.x * 4 + w;
    if (dst >= N) return;
    int s = offs[dst], cntE = offs[dst + 1] - s;

    float den[4] = {0.f, 0.f, 0.f, 0.f};
    for (int i = 0; i < cntE; ++i) {
        #pragma unroll
        for (int h = 0; h < 4; ++h) den[h] += expf(logits[(s + i) * 4 + h]);
    }
    float acc[8] = {0.f, 0.f, 0.f, 0.f, 0.f, 0.f, 0.f, 0.f};
    for (int i = 0; i < cntE; ++i) {
        int p = s + i;
        int src = ssrc[p];
        #pragma unroll
        for (int h = 0; h < 4; ++h) {
            float al = expf(logits[p * 4 + h]) / (den[h] + 1e-16f);
            uint4 q = *(const uint4*)((const unsigned short*)Y
                        + ((size_t)src * 4 + h) * 512 + lane * 8);
            acc[0] += al * bfu((unsigned short)(q.x & 0xffff));
            acc[1] += al * bfu((unsigned short)(q.x >> 16));
            acc[2] += al * bfu((unsigned short)(q.y & 0xffff));
            acc[3] += al * bfu((unsigned short)(q.y >> 16));
            acc[4] += al * bfu((unsigned short)(q.z & 0xffff));
            acc[5] += al * bfu((unsigned short)(q.z >> 16));
            acc[6] += al * bfu((unsigned short)(q.w & 0xffff));
            acc[7] += al * bfu((unsigned short)(q.w >> 16));
        }
    }
    float gate = (cntE > 0) ? 1.f : 0.f;
    float p6[6] = {0.f, 0.f, 0.f, 0.f, 0.f, 0.f};
    #pragma unroll
    for (int j = 0; j < 8; ++j) {
        int c = lane * 8 + j;
        float u = fmaxf(acc[j] + bias2[c] + gate * blw[c], 0.f);
        #pragma unroll
        for (int jj = 0; jj < 6; ++jj) p6[jj] += u * wds[c * 6 + jj];
    }
    #pragma unroll
    for (int off = 32; off; off >>= 1)
        #pragma unroll
        for (int jj = 0; jj < 6; ++jj) p6[jj] += __shfl_down(p6[jj], off);
    if (lane == 0) {
        #pragma unroll
        for (int jj = 0; jj < 6; ++jj)
            out[(size_t)dst * 6 + jj] = 1.f / (1.f + expf(-(p6[jj] + bd2[jj])));
    }
}

extern "C" void kernel_launch(void* const* d_in, const int* in_sizes, int n_in,
                              void* d_out, int out_size, void* d_ws, size_t ws_size,
                              hipStream_t stream)
{
    const float* x         = (const float*)d_in[0];
    const float* edge_attr = (const float*)d_in[1];
    const int*   ei        = (const int*)d_in[2];
    const float* W_node = (const float*)d_in[3],  *b_node = (const float*)d_in[4];
    const float* W_edge = (const float*)d_in[5],  *b_edge = (const float*)d_in[6];
    const float* W_l    = (const float*)d_in[7],  *b_l    = (const float*)d_in[8];
    const float* W_r    = (const float*)d_in[9],  *b_r    = (const float*)d_in[10];
    const float* W_le   = (const float*)d_in[11];
    const float* att    = (const float*)d_in[12];
    const float* conv_bias = (const float*)d_in[13];
    const float* W_d1   = (const float*)d_in[14], *b_d1 = (const float*)d_in[15];
    const float* W_d2   = (const float*)d_in[16], *b_d2 = (const float*)d_in[17];
    float* out = (float*)d_out;

    const int N = in_sizes[0] / 7;   // 25000
    const int E = in_sizes[1] / 2;   // 50000
    const int MP = (N + 127) & ~127;
    const int EP = (E + 127) & ~127;

    // ---- workspace layout (~268 MB, round-12 plan) ----
    char* ws = (char*)d_ws;
    const size_t szR0 = (size_t)EP * 512 * 2;
    const size_t szX  = (size_t)MP * 2048 * 2;
    const size_t szW  = (size_t)2048 * 512 * 2;   // 2 MB
    const size_t szlg = (size_t)E * 4 * 4;
    const size_t szI  = (((size_t)(N + 1) * 4) + 15) & ~(size_t)15;
    const size_t o_XL = szR0;
    const size_t o_XR = o_XL + szX;
    const size_t o_W  = o_XR + szX;                // WlT, WrT, WleT, WcombT
    const size_t o_lg = o_W + 4 * szW;
    const size_t o_b2 = o_lg + szlg;
    const size_t o_blw = o_b2 + 2048;
    const size_t o_bc = o_blw + 2048;
    const size_t o_cnt = o_bc + 4096 * 4;
    const size_t o_cnt2 = o_cnt + szI;
    const size_t o_off = o_cnt2 + szI;
    const size_t o_el = o_off + szI;
    const size_t o_ss = o_el + (size_t)E * 4;
    const size_t o_sd = o_ss + (size_t)E * 4;
    const size_t need = o_sd + (size_t)E * 4;
    if (ws_size < need) return;   // clean diagnostic failure if ws too small

    __hip_bfloat16* h   = (__hip_bfloat16*)ws;      // region0
    __hip_bfloat16* ea  = (__hip_bfloat16*)ws;      // region0 (overlays h)
    __hip_bfloat16* XL  = (__hip_bfloat16*)(ws + o_XL);
    __hip_bfloat16* XR  = (__hip_bfloat16*)(ws + o_XR);
    __hip_bfloat16* Y   = XR;                       // overlays XR after logits
    __hip_bfloat16* WlT = (__hip_bfloat16*)(ws + o_W);
    __hip_bfloat16* WrT = WlT + szW / 2;
    __hip_bfloat16* WleT= WrT + szW / 2;
    __hip_bfloat16* WcombT = WleT + szW / 2;        // [2048,512]
    __hip_bfloat16* Wd1T_t = (__hip_bfloat16*)(ws + o_XL);           // transient
    __hip_bfloat16* Wlbf_t = (__hip_bfloat16*)(ws + o_XL + szW);     // transient
    float* logits = (float*)(ws + o_lg);
    float* bias2  = (float*)(ws + o_b2);
    float* blw    = (float*)(ws + o_blw);
    float* bcat   = (float*)(ws + o_bc);
    int* cnt   = (int*)(ws + o_cnt);
    int* cnt2  = (int*)(ws + o_cnt2);
    int* offs  = (int*)(ws + o_off);
    int* elist = (int*)(ws + o_el);
    int* ssrc  = (int*)(ws + o_ss);
    int* sdst  = (int*)(ws + o_sd);

    hipMemsetAsync(logits, 0, szlg, stream);
    hipMemsetAsync(cnt, 0, szI, stream);
    hipMemsetAsync(cnt2, 0, szI, stream);
    hipMemcpyAsync(bcat, b_l, 2048 * 4, hipMemcpyDeviceToDevice, stream);
    hipMemcpyAsync(bcat + 2048, b_r, 2048 * 4, hipMemcpyDeviceToDevice, stream);

    // ---- weight prep ----
    dim3 gT(512 / 32, 2048 / 32);
    transpose_bf16<<<gT, 256, 0, stream>>>(W_l,  WlT, 512, 2048);
    transpose_bf16<<<gT, 256, 0, stream>>>(W_r,  WrT, 512, 2048);
    transpose_bf16<<<gT, 256, 0, stream>>>(W_le, WleT, 512, 2048);
    dim3 gT2(2048 / 32, 512 / 32);
    transpose_bf16<<<gT2, 256, 0, stream>>>(W_d1, Wd1T_t, 2048, 512);
    cast_bf16<<<(512 * 2048 + 255) / 256, 256, 0, stream>>>(W_l, Wlbf_t, 512 * 2048);

    // WcombT[hz*512+j, k] = sum_c W_d1[hz*512+c, j] * W_l[k, hz*512+c]
    dim3 gWc(512 / 128, 512 / 128, 4);
    mfma_gemm<__hip_bfloat16, false><<<gWc, 256, 0, stream>>>(
        Wd1T_t, 2048, 512, Wlbf_t, 2048, 512, nullptr, 0,
        WcombT, 512, (long)512 * 512, 512, 512);

    bias_init<<<2, 256, 0, stream>>>(b_d1, bias2, blw);
    bias_acc<<<32, 256, 0, stream>>>(conv_bias, b_l, W_d1, bias2, blw);

    // ---- counting sort of edges by dst ----
    count_dst<<<(E + 255) / 256, 256, 0, stream>>>(ei, cnt, E);
    scan_kernel<<<1, 1024, 0, stream>>>(cnt, offs, N);
    fill_elist<<<(E + 255) / 256, 256, 0, stream>>>(ei, offs, cnt2, elist, ssrc, sdst, E);

    // ---- h(1) -> XL/XR ----
    encode_nodes<<<(N * 512 + 255) / 256, 256, 0, stream>>>(x, W_node, b_node, h, N);

    const int MB = MP / 128;
    dim3 gNode(2048 / 128, MB, 2);
    mfma_gemm<__hip_bfloat16, true><<<gNode, 256, 0, stream>>>(
        h, 512, 0, WlT, 512, (long)2048 * 512, bcat, 2048,
        XL, 2048, (long)MP * 2048, N, 512);

    // ---- ea (overlays h) -> edge logits (1D grid, XCD swizzle) ----
    encode_edges_sorted<<<(E * 512 + 255) / 256, 256, 0, stream>>>(
        edge_attr, elist, W_edge, b_edge, ea, E);

    edge_mfma_logits<<<16 * (EP / 128), 256, 0, stream>>>(
        ea, WleT, XL, XR, ssrc, sdst, att, logits, E);

    // ---- h(2) (overlays ea) -> Y = h @ WcombT (Y overlays dead XR) ----
    encode_nodes<<<(N * 512 + 255) / 256, 256, 0, stream>>>(x, W_node, b_node, h, N);

    dim3 gY(2048 / 128, MB);
    mfma_gemm<__hip_bfloat16, false><<<gY, 256, 0, stream>>>(
        h, 512, 0, WcombT, 512, 0, nullptr, 0, Y, 2048, 0, N, 512);

    gat_out<<<(N + 3) / 4, 256, 0, stream>>>(Y, ssrc, offs, logits,
                                             bias2, blw, W_d2, b_d2, out, N);
}

// Round 17
// 712.298 us; speedup vs baseline: 1.1936x; 1.1635x over previous
//
#include <hip/hip_runtime.h>
#include <hip/hip_bf16.h>

typedef __attribute__((ext_vector_type(8))) short short8;
typedef __attribute__((ext_vector_type(4))) float f32x4;
typedef unsigned int uint32;

#define GLD16(g, l) __builtin_amdgcn_global_load_lds( \
    (const __attribute__((address_space(1))) unsigned int*)(g), \
    (__attribute__((address_space(3))) unsigned int*)(l), 16, 0, 0)

__device__ __forceinline__ float bfu(unsigned short u) {
    union { uint32 v; float f; } x; x.v = ((uint32)u) << 16; return x.f;
}
__device__ __forceinline__ void storev(float* p, float v) { *p = v; }
__device__ __forceinline__ void storev(__hip_bfloat16* p, float v) { *p = __float2bfloat16(v); }

// ============ transpose fp32 [K,N] -> bf16 [N,K] ============
__global__ __launch_bounds__(256) void transpose_bf16(
    const float* __restrict__ W, __hip_bfloat16* __restrict__ WT, int K, int N)
{
    __shared__ float tile[32][33];
    int k0 = blockIdx.x * 32, n0 = blockIdx.y * 32;
    int tx = threadIdx.x & 31, ty = threadIdx.x >> 5;   // 32 x 8
    #pragma unroll
    for (int i = 0; i < 32; i += 8)
        tile[ty + i][tx] = W[(size_t)(k0 + ty + i) * N + n0 + tx];
    __syncthreads();
    #pragma unroll
    for (int i = 0; i < 32; i += 8)
        WT[(size_t)(n0 + ty + i) * K + k0 + tx] = __float2bfloat16(tile[tx][ty + i]);
}

__global__ __launch_bounds__(256) void cast_bf16(
    const float* __restrict__ W, __hip_bfloat16* __restrict__ O, int total)
{
    int idx = blockIdx.x * 256 + threadIdx.x;
    if (idx < total) O[idx] = __float2bfloat16(W[idx]);
}

// ============ encoders ============
__global__ __launch_bounds__(256) void encode_nodes(
    const float* __restrict__ x, const float* __restrict__ Wn,
    const float* __restrict__ bn, __hip_bfloat16* __restrict__ h, int Nn)
{
    int idx = blockIdx.x * 256 + threadIdx.x;
    if (idx >= Nn * 512) return;
    int n = idx >> 9, c = idx & 511;
    float acc = bn[c];
    #pragma unroll
    for (int f = 0; f < 7; ++f) acc += x[n * 7 + f] * Wn[f * 512 + c];
    h[idx] = __float2bfloat16(fmaxf(acc, 0.f));
}

__global__ __launch_bounds__(256) void encode_edges_sorted(
    const float* __restrict__ eat, const int* __restrict__ elist,
    const float* __restrict__ We, const float* __restrict__ be,
    __hip_bfloat16* __restrict__ ea, int E)
{
    int idx = blockIdx.x * 256 + threadIdx.x;
    if (idx >= E * 512) return;
    int p = idx >> 9, c = idx & 511;
    int e = elist[p];
    float v = fmaf(eat[e * 2], We[c], fmaf(eat[e * 2 + 1], We[512 + c], be[c]));
    ea[idx] = __float2bfloat16(fmaxf(v, 0.f));
}

// ============ bf16 MFMA GEMM, BK=64 ============
template <typename OutT, bool HAS_BIAS>
__global__ __launch_bounds__(256) void mfma_gemm(
    const __hip_bfloat16* __restrict__ A, int lda, long az,
    const __hip_bfloat16* __restrict__ BT, int ldb, long bz,
    const float* __restrict__ bias, long biasz,
    OutT* __restrict__ C, int ldc, long cz, int M, int K)
{
    __shared__ uint4 As4[1024];   // 16 KB
    __shared__ uint4 Bs4[1024];
    A  += (long)blockIdx.z * az;
    BT += (long)blockIdx.z * bz;
    C  += (long)blockIdx.z * cz;
    if (HAS_BIAS) bias += (long)blockIdx.z * biasz;
    const int t = threadIdx.x, lane = t & 63, w = t >> 6;
    const int wr = (w >> 1) * 64, wc = (w & 1) * 64;
    const int col0 = blockIdx.x * 128, row0 = blockIdx.y * 128;  // x = col tile (fast)
    const int lr = lane & 15, lg = lane >> 4;
    const int srow8 = lane >> 3;
    const int sch   = (lane & 7) ^ srow8;
    const int rx = lr & 7;

    const __hip_bfloat16* ApL = A + (size_t)(row0 + srow8) * lda + sch * 8;
    const __hip_bfloat16* BpL = BT + (size_t)(col0 + srow8) * ldb + sch * 8;

    f32x4 acc[4][4];
    #pragma unroll
    for (int m = 0; m < 4; ++m)
        #pragma unroll
        for (int n = 0; n < 4; ++n) acc[m][n] = 0.f;

    for (int k0 = 0; k0 < K; k0 += 64) {
        #pragma unroll
        for (int j = 0; j < 4; ++j) {
            int rb = (w + 4 * j) * 8;
            GLD16(ApL + (size_t)rb * lda + k0, As4 + (w + 4 * j) * 64);
            GLD16(BpL + (size_t)rb * ldb + k0, Bs4 + (w + 4 * j) * 64);
        }
        __syncthreads();
        #pragma unroll
        for (int kk = 0; kk < 2; ++kk) {
            short8 af[4], bfrag[4];
            #pragma unroll
            for (int m = 0; m < 4; ++m) {
                int row = wr + m * 16 + lr;
                af[m] = *(const short8*)((const char*)As4 + row * 128 + (((kk * 4 + lg) ^ rx) << 4));
            }
            #pragma unroll
            for (int n = 0; n < 4; ++n) {
                int row = wc + n * 16 + lr;
                bfrag[n] = *(const short8*)((const char*)Bs4 + row * 128 + (((kk * 4 + lg) ^ rx) << 4));
            }
            #pragma unroll
            for (int m = 0; m < 4; ++m)
                #pragma unroll
                for (int n = 0; n < 4; ++n)
                    acc[m][n] = __builtin_amdgcn_mfma_f32_16x16x32_bf16(af[m], bfrag[n], acc[m][n], 0, 0, 0);
        }
        __syncthreads();
    }

    #pragma unroll
    for (int m = 0; m < 4; ++m) {
        #pragma unroll
        for (int r = 0; r < 4; ++r) {
            int gr = row0 + wr + m * 16 + lg * 4 + r;
            if (gr >= M) continue;
            #pragma unroll
            for (int n = 0; n < 4; ++n) {
                int gc = col0 + wc + n * 16 + lr;
                float v = acc[m][n][r];
                if (HAS_BIAS) v += bias[gc];
                storev(&C[(size_t)gr * ldc + gc], v);
            }
        }
    }
}

// ============ edge GEMM (BK=64) + fused logits, sorted-edge space ============
__global__ __launch_bounds__(256) void edge_mfma_logits(
    const __hip_bfloat16* __restrict__ ea,
    const __hip_bfloat16* __restrict__ WleT,
    const __hip_bfloat16* __restrict__ XL,
    const __hip_bfloat16* __restrict__ XR,
    const int* __restrict__ ssrc,
    const int* __restrict__ sdst,
    const float* __restrict__ att,
    float* __restrict__ logits,
    int E)
{
    __shared__ uint4 As4[1024];
    __shared__ uint4 Bs4[1024];
    __shared__ int srcs[128], dsts[128];
    const int t = threadIdx.x, lane = t & 63, w = t >> 6;
    const int wr = (w >> 1) * 64, wc = (w & 1) * 64;
    const int col0 = blockIdx.x * 128, row0 = blockIdx.y * 128;
    const int lr = lane & 15, lg = lane >> 4;
    const int srow8 = lane >> 3;
    const int sch   = (lane & 7) ^ srow8;
    const int rx = lr & 7;

    if (t < 128) {
        int ge = row0 + t;
        bool ok = ge < E;
        srcs[t] = ok ? ssrc[ge] : 0;
        dsts[t] = ok ? sdst[ge] : 0;
    }
    const __hip_bfloat16* ApL = ea + (size_t)(row0 + srow8) * 512 + sch * 8;
    const __hip_bfloat16* BpL = WleT + (size_t)(col0 + srow8) * 512 + sch * 8;
    __syncthreads();

    f32x4 acc[4][4];
    #pragma unroll
    for (int m = 0; m < 4; ++m)
        #pragma unroll
        for (int n = 0; n < 4; ++n) acc[m][n] = 0.f;

    for (int k0 = 0; k0 < 512; k0 += 64) {
        #pragma unroll
        for (int j = 0; j < 4; ++j) {
            int rb = (w + 4 * j) * 8;
            GLD16(ApL + (size_t)rb * 512 + k0, As4 + (w + 4 * j) * 64);
            GLD16(BpL + (size_t)rb * 512 + k0, Bs4 + (w + 4 * j) * 64);
        }
        __syncthreads();
        #pragma unroll
        for (int kk = 0; kk < 2; ++kk) {
            short8 af[4], bfrag[4];
            #pragma unroll
            for (int m = 0; m < 4; ++m) {
                int row = wr + m * 16 + lr;
                af[m] = *(const short8*)((const char*)As4 + row * 128 + (((kk * 4 + lg) ^ rx) << 4));
            }
            #pragma unroll
            for (int n = 0; n < 4; ++n) {
                int row = wc + n * 16 + lr;
                bfrag[n] = *(const short8*)((const char*)Bs4 + row * 128 + (((kk * 4 + lg) ^ rx) << 4));
            }
            #pragma unroll
            for (int m = 0; m < 4; ++m)
                #pragma unroll
                for (int n = 0; n < 4; ++n)
                    acc[m][n] = __builtin_amdgcn_mfma_f32_16x16x32_bf16(af[m], bfrag[n], acc[m][n], 0, 0, 0);
        }
        __syncthreads();
    }

    const int hh = col0 >> 9;
    float attv[4];
    #pragma unroll
    for (int n = 0; n < 4; ++n)
        attv[n] = att[hh * 512 + ((col0 + wc + n * 16 + lr) & 511)];
    float part[4][4];
    #pragma unroll
    for (int m = 0; m < 4; ++m)
        #pragma unroll
        for (int r = 0; r < 4; ++r) part[m][r] = 0.f;

    const int prt = (lane & 3) * 8;
    const int r0e = w * 16 + (lane >> 2);
    const int s0 = srcs[r0e], s1 = srcs[r0e + 64];
    const int d0 = dsts[r0e], d1 = dsts[r0e + 64];

    #pragma unroll
    for (int pair = 0; pair < 2; ++pair) {
        #pragma unroll
        for (int sp = 0; sp < 2; ++sp) {
            int ch = pair + sp * 2;
            int cc = col0 + ch * 32;
            GLD16(XL + (size_t)s0 * 2048 + cc + prt, As4 + sp * 512 + w * 64);
            GLD16(XL + (size_t)s1 * 2048 + cc + prt, As4 + sp * 512 + (w + 4) * 64);
            GLD16(XR + (size_t)d0 * 2048 + cc + prt, Bs4 + sp * 512 + w * 64);
            GLD16(XR + (size_t)d1 * 2048 + cc + prt, Bs4 + sp * 512 + (w + 4) * 64);
        }
        __syncthreads();
        #pragma unroll
        for (int sp = 0; sp < 2; ++sp) {
            int ch = pair + sp * 2;
            const char* AsB = (const char*)(As4 + sp * 512);
            const char* BsB = (const char*)(Bs4 + sp * 512);
            #pragma unroll
            for (int n = 0; n < 4; ++n) {
                if (((wc + n * 16) >> 5) != ch) continue;
                int colin = ((n & 1) << 4) + lr;
                #pragma unroll
                for (int m = 0; m < 4; ++m) {
                    #pragma unroll
                    for (int r = 0; r < 4; ++r) {
                        int row = wr + m * 16 + lg * 4 + r;
                        float xl = bfu(*(const unsigned short*)(AsB + row * 64 + colin * 2));
                        float xr = bfu(*(const unsigned short*)(BsB + row * 64 + colin * 2));
                        float mv = acc[m][n][r] + xl + xr;
                        part[m][r] += attv[n] * ((mv > 0.f) ? mv : 0.2f * mv);
                    }
                }
            }
        }
        __syncthreads();
    }
    #pragma unroll
    for (int m = 0; m < 4; ++m) {
        #pragma unroll
        for (int r = 0; r < 4; ++r) {
            float p = part[m][r];
            p += __shfl_xor(p, 1); p += __shfl_xor(p, 2);
            p += __shfl_xor(p, 4); p += __shfl_xor(p, 8);
            int ge = row0 + wr + m * 16 + lg * 4 + r;
            if (lr == 0 && ge < E) atomicAdd(&logits[ge * 4 + hh], p);
        }
    }
}

// ============ counting sort ============
__global__ __launch_bounds__(256) void count_dst(
    const int* __restrict__ ei, int* __restrict__ cnt, int E)
{
    int e = blockIdx.x * 256 + threadIdx.x;
    if (e < E) atomicAdd(&cnt[ei[E + e]], 1);
}

__global__ __launch_bounds__(1024) void scan_kernel(
    const int* __restrict__ cnt, int* __restrict__ offs, int N)
{
    __shared__ int wsum[16];
    __shared__ int stot;
    __shared__ int carry_s;
    int t = threadIdx.x, lane = t & 63, w = t >> 6;
    if (t == 0) carry_s = 0;
    __syncthreads();
    for (int base = 0; base < N; base += 1024) {
        int v = (base + t < N) ? cnt[base + t] : 0;
        int x = v;
        #pragma unroll
        for (int off = 1; off < 64; off <<= 1) {
            int y = __shfl_up(x, off);
            if (lane >= off) x += y;
        }
        if (lane == 63) wsum[w] = x;
        __syncthreads();
        if (w == 0 && lane < 16) {
            int v0 = wsum[lane];
            int s = v0;
            #pragma unroll
            for (int off = 1; off < 16; off <<= 1) {
                int y = __shfl_up(s, off);
                if (lane >= off) s += y;
            }
            wsum[lane] = s - v0;
            if (lane == 15) stot = s;
        }
        __syncthreads();
        if (base + t < N) offs[base + t] = carry_s + wsum[w] + x - v;
        __syncthreads();
        if (t == 0) carry_s += stot;
    }
    __syncthreads();
    if (t == 0) offs[N] = carry_s;
}

__global__ __launch_bounds__(256) void fill_elist(
    const int* __restrict__ ei, const int* __restrict__ offs,
    int* __restrict__ cnt2, int* __restrict__ elist,
    int* __restrict__ ssrc, int* __restrict__ sdst, int E)
{
    int e = blockIdx.x * 256 + threadIdx.x;
    if (e >= E) return;
    int d = ei[E + e];
    int p = offs[d] + atomicAdd(&cnt2[d], 1);
    elist[p] = e;
    ssrc[p] = ei[e];
    sdst[p] = d;
}

// ============ bias prep ============
__global__ __launch_bounds__(256) void bias_init(
    const float* __restrict__ bd1, float* __restrict__ bias2, float* __restrict__ blw)
{
    int j = blockIdx.x * 256 + threadIdx.x;
    if (j < 512) { bias2[j] = bd1[j]; blw[j] = 0.f; }
}
__global__ __launch_bounds__(256) void bias_acc(
    const float* __restrict__ cb, const float* __restrict__ bl,
    const float* __restrict__ Wd1, float* __restrict__ bias2, float* __restrict__ blw)
{
    int g = blockIdx.x * 256 + threadIdx.x;   // 8192 threads: 512 j x 16 slices
    int j = g & 511, slice = g >> 9;
    float pa = 0.f, pb = 0.f;
    for (int k = slice * 128; k < slice * 128 + 128; ++k) {
        float wv = Wd1[(size_t)k * 512 + j];
        pa += cb[k] * wv;
        pb += bl[k] * wv;
    }
    atomicAdd(&bias2[j], pa);
    atomicAdd(&blw[j], pb);
}

// ============ fused output ============
__global__ __launch_bounds__(256) void gat_out(
    const __hip_bfloat16* __restrict__ Y,     // [N,4,512] bf16 (no bias terms)
    const int* __restrict__ ssrc, const int* __restrict__ offs,
    const float* __restrict__ logits,         // [E,4] sorted
    const float* __restrict__ bias2, const float* __restrict__ blw,
    const float* __restrict__ Wd2,
    const float* __restrict__ bd2,
    float* __restrict__ out, int N)
{
    __shared__ float wds[512 * 6];
    int t = threadIdx.x;
    for (int i = t; i < 512 * 6; i += 256) wds[i] = Wd2[i];
    __syncthreads();
    int w = t >> 6, lane = t & 63;
    int dst = blockIdx.x * 4 + w;
    if (dst >= N) return;
    int s = offs[dst], cntE = offs[dst + 1] - s;

    float den[4] = {0.f, 0.f, 0.f, 0.f};
    for (int i = 0; i < cntE; ++i) {
        #pragma unroll
        for (int h = 0; h < 4; ++h) den[h] += expf(logits[(s + i) * 4 + h]);
    }
    float acc[8] = {0.f, 0.f, 0.f, 0.f, 0.f, 0.f, 0.f, 0.f};
    for (int i = 0; i < cntE; ++i) {
        int p = s + i;
        int src = ssrc[p];
        #pragma unroll
        for (int h = 0; h < 4; ++h) {
            float al = expf(logits[p * 4 + h]) / (den[h] + 1e-16f);
            uint4 q = *(const uint4*)((const unsigned short*)Y
                        + ((size_t)src * 4 + h) * 512 + lane * 8);
            acc[0] += al * bfu((unsigned short)(q.x & 0xffff));
            acc[1] += al * bfu((unsigned short)(q.x >> 16));
            acc[2] += al * bfu((unsigned short)(q.y & 0xffff));
            acc[3] += al * bfu((unsigned short)(q.y >> 16));
            acc[4] += al * bfu((unsigned short)(q.z & 0xffff));
            acc[5] += al * bfu((unsigned short)(q.z >> 16));
            acc[6] += al * bfu((unsigned short)(q.w & 0xffff));
            acc[7] += al * bfu((unsigned short)(q.w >> 16));
        }
    }
    float gate = (cntE > 0) ? 1.f : 0.f;
    float p6[6] = {0.f, 0.f, 0.f, 0.f, 0.f, 0.f};
    #pragma unroll
    for (int j = 0; j < 8; ++j) {
        int c = lane * 8 + j;
        float u = fmaxf(acc[j] + bias2[c] + gate * blw[c], 0.f);
        #pragma unroll
        for (int jj = 0; jj < 6; ++jj) p6[jj] += u * wds[c * 6 + jj];
    }
    #pragma unroll
    for (int off = 32; off; off >>= 1)
        #pragma unroll
        for (int jj = 0; jj < 6; ++jj) p6[jj] += __shfl_down(p6[jj], off);
    if (lane == 0) {
        #pragma unroll
        for (int jj = 0; jj < 6; ++jj)
            out[(size_t)dst * 6 + jj] = 1.f / (1.f + expf(-(p6[jj] + bd2[jj])));
    }
}

extern "C" void kernel_launch(void* const* d_in, const int* in_sizes, int n_in,
                              void* d_out, int out_size, void* d_ws, size_t ws_size,
                              hipStream_t stream)
{
    const float* x         = (const float*)d_in[0];
    const float* edge_attr = (const float*)d_in[1];
    const int*   ei        = (const int*)d_in[2];
    const float* W_node = (const float*)d_in[3],  *b_node = (const float*)d_in[4];
    const float* W_edge = (const float*)d_in[5],  *b_edge = (const float*)d_in[6];
    const float* W_l    = (const float*)d_in[7],  *b_l    = (const float*)d_in[8];
    const float* W_r    = (const float*)d_in[9],  *b_r    = (const float*)d_in[10];
    const float* W_le   = (const float*)d_in[11];
    const float* att    = (const float*)d_in[12];
    const float* conv_bias = (const float*)d_in[13];
    const float* W_d1   = (const float*)d_in[14], *b_d1 = (const float*)d_in[15];
    const float* W_d2   = (const float*)d_in[16], *b_d2 = (const float*)d_in[17];
    float* out = (float*)d_out;

    const int N = in_sizes[0] / 7;   // 25000
    const int E = in_sizes[1] / 2;   // 50000
    const int MP = (N + 127) & ~127;
    const int EP = (E + 127) & ~127;

    // ---- workspace layout (~268 MB, round-12 plan) ----
    char* ws = (char*)d_ws;
    const size_t szR0 = (size_t)EP * 512 * 2;
    const size_t szX  = (size_t)MP * 2048 * 2;
    const size_t szW  = (size_t)2048 * 512 * 2;   // 2 MB
    const size_t szlg = (size_t)E * 4 * 4;
    const size_t szI  = (((size_t)(N + 1) * 4) + 15) & ~(size_t)15;
    const size_t o_XL = szR0;
    const size_t o_XR = o_XL + szX;
    const size_t o_W  = o_XR + szX;                // WlT, WrT, WleT, WcombT
    const size_t o_lg = o_W + 4 * szW;
    const size_t o_b2 = o_lg + szlg;
    const size_t o_blw = o_b2 + 2048;
    const size_t o_bc = o_blw + 2048;
    const size_t o_cnt = o_bc + 4096 * 4;
    const size_t o_cnt2 = o_cnt + szI;
    const size_t o_off = o_cnt2 + szI;
    const size_t o_el = o_off + szI;
    const size_t o_ss = o_el + (size_t)E * 4;
    const size_t o_sd = o_ss + (size_t)E * 4;
    const size_t need = o_sd + (size_t)E * 4;
    if (ws_size < need) return;   // clean diagnostic failure if ws too small

    __hip_bfloat16* h   = (__hip_bfloat16*)ws;      // region0
    __hip_bfloat16* ea  = (__hip_bfloat16*)ws;      // region0 (overlays h)
    __hip_bfloat16* XL  = (__hip_bfloat16*)(ws + o_XL);
    __hip_bfloat16* XR  = (__hip_bfloat16*)(ws + o_XR);
    __hip_bfloat16* Y   = XR;                       // overlays XR after logits
    __hip_bfloat16* WlT = (__hip_bfloat16*)(ws + o_W);
    __hip_bfloat16* WrT = WlT + szW / 2;
    __hip_bfloat16* WleT= WrT + szW / 2;
    __hip_bfloat16* WcombT = WleT + szW / 2;        // [2048,512]
    __hip_bfloat16* Wd1T_t = (__hip_bfloat16*)(ws + o_XL);           // transient
    __hip_bfloat16* Wlbf_t = (__hip_bfloat16*)(ws + o_XL + szW);     // transient
    float* logits = (float*)(ws + o_lg);
    float* bias2  = (float*)(ws + o_b2);
    float* blw    = (float*)(ws + o_blw);
    float* bcat   = (float*)(ws + o_bc);
    int* cnt   = (int*)(ws + o_cnt);
    int* cnt2  = (int*)(ws + o_cnt2);
    int* offs  = (int*)(ws + o_off);
    int* elist = (int*)(ws + o_el);
    int* ssrc  = (int*)(ws + o_ss);
    int* sdst  = (int*)(ws + o_sd);

    hipMemsetAsync(logits, 0, szlg, stream);
    hipMemsetAsync(cnt, 0, szI, stream);
    hipMemsetAsync(cnt2, 0, szI, stream);
    hipMemcpyAsync(bcat, b_l, 2048 * 4, hipMemcpyDeviceToDevice, stream);
    hipMemcpyAsync(bcat + 2048, b_r, 2048 * 4, hipMemcpyDeviceToDevice, stream);

    // ---- weight prep ----
    dim3 gT(512 / 32, 2048 / 32);
    transpose_bf16<<<gT, 256, 0, stream>>>(W_l,  WlT, 512, 2048);
    transpose_bf16<<<gT, 256, 0, stream>>>(W_r,  WrT, 512, 2048);
    transpose_bf16<<<gT, 256, 0, stream>>>(W_le, WleT, 512, 2048);
    dim3 gT2(2048 / 32, 512 / 32);
    transpose_bf16<<<gT2, 256, 0, stream>>>(W_d1, Wd1T_t, 2048, 512);
    cast_bf16<<<(512 * 2048 + 255) / 256, 256, 0, stream>>>(W_l, Wlbf_t, 512 * 2048);

    // WcombT[hz*512+j, k] = sum_c W_d1[hz*512+c, j] * W_l[k, hz*512+c]
    dim3 gWc(512 / 128, 512 / 128, 4);
    mfma_gemm<__hip_bfloat16, false><<<gWc, 256, 0, stream>>>(
        Wd1T_t, 2048, 512, Wlbf_t, 2048, 512, nullptr, 0,
        WcombT, 512, (long)512 * 512, 512, 512);

    bias_init<<<2, 256, 0, stream>>>(b_d1, bias2, blw);
    bias_acc<<<32, 256, 0, stream>>>(conv_bias, b_l, W_d1, bias2, blw);

    // ---- counting sort of edges by dst ----
    count_dst<<<(E + 255) / 256, 256, 0, stream>>>(ei, cnt, E);
    scan_kernel<<<1, 1024, 0, stream>>>(cnt, offs, N);
    fill_elist<<<(E + 255) / 256, 256, 0, stream>>>(ei, offs, cnt2, elist, ssrc, sdst, E);

    // ---- h(1) -> XL/XR ----
    encode_nodes<<<(N * 512 + 255) / 256, 256, 0, stream>>>(x, W_node, b_node, h, N);

    const int MB = MP / 128;
    dim3 gNode(2048 / 128, MB, 2);
    mfma_gemm<__hip_bfloat16, true><<<gNode, 256, 0, stream>>>(
        h, 512, 0, WlT, 512, (long)2048 * 512, bcat, 2048,
        XL, 2048, (long)MP * 2048, N, 512);

    // ---- ea (overlays h) -> edge logits ----
    encode_edges_sorted<<<(E * 512 + 255) / 256, 256, 0, stream>>>(
        edge_attr, elist, W_edge, b_edge, ea, E);

    dim3 gE(16, EP / 128);
    edge_mfma_logits<<<gE, 256, 0, stream>>>(ea, WleT, XL, XR, ssrc, sdst, att, logits, E);

    // ---- h(2) (overlays ea) -> Y = h @ WcombT (Y overlays dead XR) ----
    encode_nodes<<<(N * 512 + 255) / 256, 256, 0, stream>>>(x, W_node, b_node, h, N);

    dim3 gY(2048 / 128, MB);
    mfma_gemm<__hip_bfloat16, false><<<gY, 256, 0, stream>>>(
        h, 512, 0, WcombT, 512, 0, nullptr, 0, Y, 2048, 0, N, 512);

    gat_out<<<(N + 3) / 4, 256, 0, stream>>>(Y, ssrc, offs, logits,
                                             bias2, blw, W_d2, b_d2, out, N);
}

// Round 18
// 686.630 us; speedup vs baseline: 1.2382x; 1.0374x over previous
//
#include <hip/hip_runtime.h>
#include <hip/hip_bf16.h>

typedef __attribute__((ext_vector_type(8))) short short8;
typedef __attribute__((ext_vector_type(4))) float f32x4;
typedef unsigned int uint32;

#define GLD16(g, l) __builtin_amdgcn_global_load_lds( \
    (const __attribute__((address_space(1))) unsigned int*)(g), \
    (__attribute__((address_space(3))) unsigned int*)(l), 16, 0, 0)

__device__ __forceinline__ float bfu(unsigned short u) {
    union { uint32 v; float f; } x; x.v = ((uint32)u) << 16; return x.f;
}
__device__ __forceinline__ void storev(float* p, float v) { *p = v; }
__device__ __forceinline__ void storev(__hip_bfloat16* p, float v) { *p = __float2bfloat16(v); }

// ============ transpose fp32 [512,2048] -> bf16 [2048,512], 3 weights in z ======
__global__ __launch_bounds__(256) void transpose3_bf16(
    const float* __restrict__ W0, const float* __restrict__ W1,
    const float* __restrict__ W2, __hip_bfloat16* __restrict__ WT)
{
    __shared__ float tile[32][33];
    const float* W = (blockIdx.z == 0) ? W0 : (blockIdx.z == 1) ? W1 : W2;
    __hip_bfloat16* O = WT + (size_t)blockIdx.z * 2048 * 512;
    int k0 = blockIdx.x * 32, n0 = blockIdx.y * 32;
    int tx = threadIdx.x & 31, ty = threadIdx.x >> 5;   // 32 x 8
    #pragma unroll
    for (int i = 0; i < 32; i += 8)
        tile[ty + i][tx] = W[(size_t)(k0 + ty + i) * 2048 + n0 + tx];
    __syncthreads();
    #pragma unroll
    for (int i = 0; i < 32; i += 8)
        O[(size_t)(n0 + ty + i) * 512 + k0 + tx] = __float2bfloat16(tile[tx][ty + i]);
}

// ============ transpose fp32 [K,N] -> bf16 [N,K] (generic, for W_d1) ============
__global__ __launch_bounds__(256) void transpose_bf16(
    const float* __restrict__ W, __hip_bfloat16* __restrict__ WT, int K, int N)
{
    __shared__ float tile[32][33];
    int k0 = blockIdx.x * 32, n0 = blockIdx.y * 32;
    int tx = threadIdx.x & 31, ty = threadIdx.x >> 5;
    #pragma unroll
    for (int i = 0; i < 32; i += 8)
        tile[ty + i][tx] = W[(size_t)(k0 + ty + i) * N + n0 + tx];
    __syncthreads();
    #pragma unroll
    for (int i = 0; i < 32; i += 8)
        WT[(size_t)(n0 + ty + i) * K + k0 + tx] = __float2bfloat16(tile[tx][ty + i]);
}

__global__ __launch_bounds__(256) void cast_bf16(
    const float* __restrict__ W, __hip_bfloat16* __restrict__ O, int total)
{
    int idx = blockIdx.x * 256 + threadIdx.x;
    if (idx < total) O[idx] = __float2bfloat16(W[idx]);
}

// ============ encoders ============
__global__ __launch_bounds__(256) void encode_nodes(
    const float* __restrict__ x, const float* __restrict__ Wn,
    const float* __restrict__ bn, __hip_bfloat16* __restrict__ h, int Nn)
{
    int idx = blockIdx.x * 256 + threadIdx.x;
    if (idx >= Nn * 512) return;
    int n = idx >> 9, c = idx & 511;
    float acc = bn[c];
    #pragma unroll
    for (int f = 0; f < 7; ++f) acc += x[n * 7 + f] * Wn[f * 512 + c];
    h[idx] = __float2bfloat16(fmaxf(acc, 0.f));
}

__global__ __launch_bounds__(256) void encode_edges_sorted(
    const float* __restrict__ eat, const int* __restrict__ elist,
    const float* __restrict__ We, const float* __restrict__ be,
    __hip_bfloat16* __restrict__ ea, int E)
{
    int idx = blockIdx.x * 256 + threadIdx.x;
    if (idx >= E * 512) return;
    int p = idx >> 9, c = idx & 511;
    int e = elist[p];
    float v = fmaf(eat[e * 2], We[c], fmaf(eat[e * 2 + 1], We[512 + c], be[c]));
    ea[idx] = __float2bfloat16(fmaxf(v, 0.f));
}

// ============ bf16 MFMA GEMM, BK=64 ============
template <typename OutT, bool HAS_BIAS>
__global__ __launch_bounds__(256) void mfma_gemm(
    const __hip_bfloat16* __restrict__ A, int lda, long az,
    const __hip_bfloat16* __restrict__ BT, int ldb, long bz,
    const float* __restrict__ bias, long biasz,
    OutT* __restrict__ C, int ldc, long cz, int M, int K)
{
    __shared__ uint4 As4[1024];   // 16 KB
    __shared__ uint4 Bs4[1024];
    A  += (long)blockIdx.z * az;
    BT += (long)blockIdx.z * bz;
    C  += (long)blockIdx.z * cz;
    if (HAS_BIAS) bias += (long)blockIdx.z * biasz;
    const int t = threadIdx.x, lane = t & 63, w = t >> 6;
    const int wr = (w >> 1) * 64, wc = (w & 1) * 64;
    const int col0 = blockIdx.x * 128, row0 = blockIdx.y * 128;  // x = col tile (fast)
    const int lr = lane & 15, lg = lane >> 4;
    const int srow8 = lane >> 3;
    const int sch   = (lane & 7) ^ srow8;
    const int rx = lr & 7;

    const __hip_bfloat16* ApL = A + (size_t)(row0 + srow8) * lda + sch * 8;
    const __hip_bfloat16* BpL = BT + (size_t)(col0 + srow8) * ldb + sch * 8;

    f32x4 acc[4][4];
    #pragma unroll
    for (int m = 0; m < 4; ++m)
        #pragma unroll
        for (int n = 0; n < 4; ++n) acc[m][n] = 0.f;

    for (int k0 = 0; k0 < K; k0 += 64) {
        #pragma unroll
        for (int j = 0; j < 4; ++j) {
            int rb = (w + 4 * j) * 8;
            GLD16(ApL + (size_t)rb * lda + k0, As4 + (w + 4 * j) * 64);
            GLD16(BpL + (size_t)rb * ldb + k0, Bs4 + (w + 4 * j) * 64);
        }
        __syncthreads();
        #pragma unroll
        for (int kk = 0; kk < 2; ++kk) {
            short8 af[4], bfrag[4];
            #pragma unroll
            for (int m = 0; m < 4; ++m) {
                int row = wr + m * 16 + lr;
                af[m] = *(const short8*)((const char*)As4 + row * 128 + (((kk * 4 + lg) ^ rx) << 4));
            }
            #pragma unroll
            for (int n = 0; n < 4; ++n) {
                int row = wc + n * 16 + lr;
                bfrag[n] = *(const short8*)((const char*)Bs4 + row * 128 + (((kk * 4 + lg) ^ rx) << 4));
            }
            #pragma unroll
            for (int m = 0; m < 4; ++m)
                #pragma unroll
                for (int n = 0; n < 4; ++n)
                    acc[m][n] = __builtin_amdgcn_mfma_f32_16x16x32_bf16(af[m], bfrag[n], acc[m][n], 0, 0, 0);
        }
        __syncthreads();
    }

    #pragma unroll
    for (int m = 0; m < 4; ++m) {
        #pragma unroll
        for (int r = 0; r < 4; ++r) {
            int gr = row0 + wr + m * 16 + lg * 4 + r;
            if (gr >= M) continue;
            #pragma unroll
            for (int n = 0; n < 4; ++n) {
                int gc = col0 + wc + n * 16 + lr;
                float v = acc[m][n][r];
                if (HAS_BIAS) v += bias[gc];
                storev(&C[(size_t)gr * ldc + gc], v);
            }
        }
    }
}

// ============ edge GEMM (BK=64) + fused logits, sorted-edge space ============
__global__ __launch_bounds__(256) void edge_mfma_logits(
    const __hip_bfloat16* __restrict__ ea,
    const __hip_bfloat16* __restrict__ WleT,
    const __hip_bfloat16* __restrict__ XL,
    const __hip_bfloat16* __restrict__ XR,
    const int* __restrict__ ssrc,
    const int* __restrict__ sdst,
    const float* __restrict__ att,
    float* __restrict__ logits,
    int E)
{
    __shared__ uint4 As4[1024];
    __shared__ uint4 Bs4[1024];
    __shared__ int srcs[128], dsts[128];
    const int t = threadIdx.x, lane = t & 63, w = t >> 6;
    const int wr = (w >> 1) * 64, wc = (w & 1) * 64;
    const int col0 = blockIdx.x * 128, row0 = blockIdx.y * 128;
    const int lr = lane & 15, lg = lane >> 4;
    const int srow8 = lane >> 3;
    const int sch   = (lane & 7) ^ srow8;
    const int rx = lr & 7;

    if (t < 128) {
        int ge = row0 + t;
        bool ok = ge < E;
        srcs[t] = ok ? ssrc[ge] : 0;
        dsts[t] = ok ? sdst[ge] : 0;
    }
    const __hip_bfloat16* ApL = ea + (size_t)(row0 + srow8) * 512 + sch * 8;
    const __hip_bfloat16* BpL = WleT + (size_t)(col0 + srow8) * 512 + sch * 8;
    __syncthreads();

    f32x4 acc[4][4];
    #pragma unroll
    for (int m = 0; m < 4; ++m)
        #pragma unroll
        for (int n = 0; n < 4; ++n) acc[m][n] = 0.f;

    for (int k0 = 0; k0 < 512; k0 += 64) {
        #pragma unroll
        for (int j = 0; j < 4; ++j) {
            int rb = (w + 4 * j) * 8;
            GLD16(ApL + (size_t)rb * 512 + k0, As4 + (w + 4 * j) * 64);
            GLD16(BpL + (size_t)rb * 512 + k0, Bs4 + (w + 4 * j) * 64);
        }
        __syncthreads();
        #pragma unroll
        for (int kk = 0; kk < 2; ++kk) {
            short8 af[4], bfrag[4];
            #pragma unroll
            for (int m = 0; m < 4; ++m) {
                int row = wr + m * 16 + lr;
                af[m] = *(const short8*)((const char*)As4 + row * 128 + (((kk * 4 + lg) ^ rx) << 4));
            }
            #pragma unroll
            for (int n = 0; n < 4; ++n) {
                int row = wc + n * 16 + lr;
                bfrag[n] = *(const short8*)((const char*)Bs4 + row * 128 + (((kk * 4 + lg) ^ rx) << 4));
            }
            #pragma unroll
            for (int m = 0; m < 4; ++m)
                #pragma unroll
                for (int n = 0; n < 4; ++n)
                    acc[m][n] = __builtin_amdgcn_mfma_f32_16x16x32_bf16(af[m], bfrag[n], acc[m][n], 0, 0, 0);
        }
        __syncthreads();
    }

    const int hh = col0 >> 9;
    float attv[4];
    #pragma unroll
    for (int n = 0; n < 4; ++n)
        attv[n] = att[hh * 512 + ((col0 + wc + n * 16 + lr) & 511)];
    float part[4][4];
    #pragma unroll
    for (int m = 0; m < 4; ++m)
        #pragma unroll
        for (int r = 0; r < 4; ++r) part[m][r] = 0.f;

    const int prt = (lane & 3) * 8;
    const int r0e = w * 16 + (lane >> 2);
    const int s0 = srcs[r0e], s1 = srcs[r0e + 64];
    const int d0 = dsts[r0e], d1 = dsts[r0e + 64];

    #pragma unroll
    for (int pair = 0; pair < 2; ++pair) {
        #pragma unroll
        for (int sp = 0; sp < 2; ++sp) {
            int ch = pair + sp * 2;
            int cc = col0 + ch * 32;
            GLD16(XL + (size_t)s0 * 2048 + cc + prt, As4 + sp * 512 + w * 64);
            GLD16(XL + (size_t)s1 * 2048 + cc + prt, As4 + sp * 512 + (w + 4) * 64);
            GLD16(XR + (size_t)d0 * 2048 + cc + prt, Bs4 + sp * 512 + w * 64);
            GLD16(XR + (size_t)d1 * 2048 + cc + prt, Bs4 + sp * 512 + (w + 4) * 64);
        }
        __syncthreads();
        #pragma unroll
        for (int sp = 0; sp < 2; ++sp) {
            int ch = pair + sp * 2;
            const char* AsB = (const char*)(As4 + sp * 512);
            const char* BsB = (const char*)(Bs4 + sp * 512);
            #pragma unroll
            for (int n = 0; n < 4; ++n) {
                if (((wc + n * 16) >> 5) != ch) continue;
                int colin = ((n & 1) << 4) + lr;
                #pragma unroll
                for (int m = 0; m < 4; ++m) {
                    #pragma unroll
                    for (int r = 0; r < 4; ++r) {
                        int row = wr + m * 16 + lg * 4 + r;
                        float xl = bfu(*(const unsigned short*)(AsB + row * 64 + colin * 2));
                        float xr = bfu(*(const unsigned short*)(BsB + row * 64 + colin * 2));
                        float mv = acc[m][n][r] + xl + xr;
                        part[m][r] += attv[n] * ((mv > 0.f) ? mv : 0.2f * mv);
                    }
                }
            }
        }
        __syncthreads();
    }
    #pragma unroll
    for (int m = 0; m < 4; ++m) {
        #pragma unroll
        for (int r = 0; r < 4; ++r) {
            float p = part[m][r];
            p += __shfl_xor(p, 1); p += __shfl_xor(p, 2);
            p += __shfl_xor(p, 4); p += __shfl_xor(p, 8);
            int ge = row0 + wr + m * 16 + lg * 4 + r;
            if (lr == 0 && ge < E) atomicAdd(&logits[ge * 4 + hh], p);
        }
    }
}

// ============ counting sort: count + 3-pass device-wide scan + fill ============
__global__ __launch_bounds__(256) void count_dst(
    const int* __restrict__ ei, int* __restrict__ cnt, int E)
{
    int e = blockIdx.x * 256 + threadIdx.x;
    if (e < E) atomicAdd(&cnt[ei[E + e]], 1);
}

__global__ __launch_bounds__(256) void scan_sums(
    const int* __restrict__ cnt, int* __restrict__ bsum, int N)
{
    __shared__ int wsums[4];
    int t = threadIdx.x;
    int idx = blockIdx.x * 256 + t;
    int v = (idx < N) ? cnt[idx] : 0;
    #pragma unroll
    for (int o = 32; o; o >>= 1) v += __shfl_down(v, o);
    if ((t & 63) == 0) wsums[t >> 6] = v;
    __syncthreads();
    if (t == 0) bsum[blockIdx.x] = wsums[0] + wsums[1] + wsums[2] + wsums[3];
}

// exclusive scan of nb (<=128) block sums in place; 1 block, 128 threads
__global__ __launch_bounds__(128) void scan_tops(int* __restrict__ bsum, int nb)
{
    __shared__ int s0;
    int t = threadIdx.x, lane = t & 63, w = t >> 6;
    int v = (t < nb) ? bsum[t] : 0;
    int x = v;
    #pragma unroll
    for (int o = 1; o < 64; o <<= 1) {
        int y = __shfl_up(x, o);
        if (lane >= o) x += y;
    }
    if (w == 0 && lane == 63) s0 = x;
    __syncthreads();
    int ex = x - v + (w ? s0 : 0);
    if (t < nb) bsum[t] = ex;
}

__global__ __launch_bounds__(256) void scan_final(
    const int* __restrict__ cnt, const int* __restrict__ boff,
    int* __restrict__ offs, int N, int E)
{
    __shared__ int wsums[4];
    int t = threadIdx.x, lane = t & 63, w = t >> 6;
    int idx = blockIdx.x * 256 + t;
    int v = (idx < N) ? cnt[idx] : 0;
    int x = v;
    #pragma unroll
    for (int o = 1; o < 64; o <<= 1) {
        int y = __shfl_up(x, o);
        if (lane >= o) x += y;
    }
    if (lane == 63) wsums[w] = x;
    __syncthreads();
    int add = boff[blockIdx.x];
    for (int i = 0; i < w; ++i) add += wsums[i];
    if (idx < N) offs[idx] = add + x - v;
    if (blockIdx.x == 0 && t == 0) offs[N] = E;   // sum(cnt) == E always
}

__global__ __launch_bounds__(256) void fill_elist(
    const int* __restrict__ ei, const int* __restrict__ offs,
    int* __restrict__ cnt2, int* __restrict__ elist,
    int* __restrict__ ssrc, int* __restrict__ sdst, int E)
{
    int e = blockIdx.x * 256 + threadIdx.x;
    if (e >= E) return;
    int d = ei[E + e];
    int p = offs[d] + atomicAdd(&cnt2[d], 1);
    elist[p] = e;
    ssrc[p] = ei[e];
    sdst[p] = d;
}

// ============ bias prep: bias2 = b_d1 + conv_bias@W_d1 ; blw = b_l@W_d1 ========
// buffers pre-zeroed; slice 0 folds in b_d1
__global__ __launch_bounds__(256) void bias_acc(
    const float* __restrict__ bd1, const float* __restrict__ cb,
    const float* __restrict__ bl, const float* __restrict__ Wd1,
    float* __restrict__ bias2, float* __restrict__ blw)
{
    int g = blockIdx.x * 256 + threadIdx.x;   // 8192 threads: 512 j x 16 slices
    int j = g & 511, slice = g >> 9;
    float pa = (slice == 0) ? bd1[j] : 0.f, pb = 0.f;
    for (int k = slice * 128; k < slice * 128 + 128; ++k) {
        float wv = Wd1[(size_t)k * 512 + j];
        pa += cb[k] * wv;
        pb += bl[k] * wv;
    }
    atomicAdd(&bias2[j], pa);
    atomicAdd(&blw[j], pb);
}

// ============ fused output ============
__global__ __launch_bounds__(256) void gat_out(
    const __hip_bfloat16* __restrict__ Y,     // [N,4,512] bf16 (no bias terms)
    const int* __restrict__ ssrc, const int* __restrict__ offs,
    const float* __restrict__ logits,         // [E,4] sorted
    const float* __restrict__ bias2, const float* __restrict__ blw,
    const float* __restrict__ Wd2,
    const float* __restrict__ bd2,
    float* __restrict__ out, int N)
{
    __shared__ float wds[512 * 6];
    int t = threadIdx.x;
    for (int i = t; i < 512 * 6; i += 256) wds[i] = Wd2[i];
    __syncthreads();
    int w = t >> 6, lane = t & 63;
    int dst = blockIdx.x * 4 + w;
    if (dst >= N) return;
    int s = offs[dst], cntE = offs[dst + 1] - s;

    float den[4] = {0.f, 0.f, 0.f, 0.f};
    for (int i = 0; i < cntE; ++i) {
        #pragma unroll
        for (int h = 0; h < 4; ++h) den[h] += expf(logits[(s + i) * 4 + h]);
    }
    float acc[8] = {0.f, 0.f, 0.f, 0.f, 0.f, 0.f, 0.f, 0.f};
    for (int i = 0; i < cntE; ++i) {
        int p = s + i;
        int src = ssrc[p];
        #pragma unroll
        for (int h = 0; h < 4; ++h) {
            float al = expf(logits[p * 4 + h]) / (den[h] + 1e-16f);
            uint4 q = *(const uint4*)((const unsigned short*)Y
                        + ((size_t)src * 4 + h) * 512 + lane * 8);
            acc[0] += al * bfu((unsigned short)(q.x & 0xffff));
            acc[1] += al * bfu((unsigned short)(q.x >> 16));
            acc[2] += al * bfu((unsigned short)(q.y & 0xffff));
            acc[3] += al * bfu((unsigned short)(q.y >> 16));
            acc[4] += al * bfu((unsigned short)(q.z & 0xffff));
            acc[5] += al * bfu((unsigned short)(q.z >> 16));
            acc[6] += al * bfu((unsigned short)(q.w & 0xffff));
            acc[7] += al * bfu((unsigned short)(q.w >> 16));
        }
    }
    float gate = (cntE > 0) ? 1.f : 0.f;
    float p6[6] = {0.f, 0.f, 0.f, 0.f, 0.f, 0.f};
    #pragma unroll
    for (int j = 0; j < 8; ++j) {
        int c = lane * 8 + j;
        float u = fmaxf(acc[j] + bias2[c] + gate * blw[c], 0.f);
        #pragma unroll
        for (int jj = 0; jj < 6; ++jj) p6[jj] += u * wds[c * 6 + jj];
    }
    #pragma unroll
    for (int off = 32; off; off >>= 1)
        #pragma unroll
        for (int jj = 0; jj < 6; ++jj) p6[jj] += __shfl_down(p6[jj], off);
    if (lane == 0) {
        #pragma unroll
        for (int jj = 0; jj < 6; ++jj)
            out[(size_t)dst * 6 + jj] = 1.f / (1.f + expf(-(p6[jj] + bd2[jj])));
    }
}

extern "C" void kernel_launch(void* const* d_in, const int* in_sizes, int n_in,
                              void* d_out, int out_size, void* d_ws, size_t ws_size,
                              hipStream_t stream)
{
    const float* x         = (const float*)d_in[0];
    const float* edge_attr = (const float*)d_in[1];
    const int*   ei        = (const int*)d_in[2];
    const float* W_node = (const float*)d_in[3],  *b_node = (const float*)d_in[4];
    const float* W_edge = (const float*)d_in[5],  *b_edge = (const float*)d_in[6];
    const float* W_l    = (const float*)d_in[7],  *b_l    = (const float*)d_in[8];
    const float* W_r    = (const float*)d_in[9],  *b_r    = (const float*)d_in[10];
    const float* W_le   = (const float*)d_in[11];
    const float* att    = (const float*)d_in[12];
    const float* conv_bias = (const float*)d_in[13];
    const float* W_d1   = (const float*)d_in[14], *b_d1 = (const float*)d_in[15];
    const float* W_d2   = (const float*)d_in[16], *b_d2 = (const float*)d_in[17];
    float* out = (float*)d_out;

    const int N = in_sizes[0] / 7;   // 25000
    const int E = in_sizes[1] / 2;   // 50000
    const int MP = (N + 127) & ~127;
    const int EP = (E + 127) & ~127;
    const int NB = (N + 255) / 256;  // scan blocks (98 <= 128)

    // ---- workspace layout (~268 MB, round-12 plan + bsum) ----
    char* ws = (char*)d_ws;
    const size_t szR0 = (size_t)EP * 512 * 2;
    const size_t szX  = (size_t)MP * 2048 * 2;
    const size_t szW  = (size_t)2048 * 512 * 2;   // 2 MB
    const size_t szlg = (size_t)E * 4 * 4;
    const size_t szI  = (((size_t)(N + 1) * 4) + 15) & ~(size_t)15;
    const size_t o_XL = szR0;
    const size_t o_XR = o_XL + szX;
    const size_t o_W  = o_XR + szX;                // WlT, WrT, WleT, WcombT
    const size_t o_lg = o_W + 4 * szW;
    const size_t o_b2 = o_lg + szlg;
    const size_t o_blw = o_b2 + 2048;
    const size_t o_bc = o_blw + 2048;
    const size_t o_cnt = o_bc + 4096 * 4;
    const size_t o_cnt2 = o_cnt + szI;
    const size_t o_off = o_cnt2 + szI;
    const size_t o_el = o_off + szI;
    const size_t o_ss = o_el + (size_t)E * 4;
    const size_t o_sd = o_ss + (size_t)E * 4;
    const size_t o_bs = o_sd + (size_t)E * 4;
    const size_t need = o_bs + 512;
    if (ws_size < need) return;   // clean diagnostic failure if ws too small

    __hip_bfloat16* h   = (__hip_bfloat16*)ws;      // region0
    __hip_bfloat16* ea  = (__hip_bfloat16*)ws;      // region0 (overlays h)
    __hip_bfloat16* XL  = (__hip_bfloat16*)(ws + o_XL);
    __hip_bfloat16* XR  = (__hip_bfloat16*)(ws + o_XR);
    __hip_bfloat16* Y   = XR;                       // overlays XR after logits
    __hip_bfloat16* WlT = (__hip_bfloat16*)(ws + o_W);
    __hip_bfloat16* WleT= WlT + szW;                // slot 2 (z-order: W_l, W_r, W_le)
    __hip_bfloat16* WcombT = (__hip_bfloat16*)(ws + o_W) + 3 * (szW / 2);
    __hip_bfloat16* Wd1T_t = (__hip_bfloat16*)(ws + o_XL);           // transient
    __hip_bfloat16* Wlbf_t = (__hip_bfloat16*)(ws + o_XL + szW);     // transient
    float* logits = (float*)(ws + o_lg);
    float* bias2  = (float*)(ws + o_b2);
    float* blw    = (float*)(ws + o_blw);
    float* bcat   = (float*)(ws + o_bc);
    int* cnt   = (int*)(ws + o_cnt);
    int* cnt2  = (int*)(ws + o_cnt2);
    int* offs  = (int*)(ws + o_off);
    int* elist = (int*)(ws + o_el);
    int* ssrc  = (int*)(ws + o_ss);
    int* sdst  = (int*)(ws + o_sd);
    int* bsum  = (int*)(ws + o_bs);

    hipMemsetAsync(logits, 0, szlg, stream);
    hipMemsetAsync(cnt, 0, szI, stream);
    hipMemsetAsync(cnt2, 0, szI, stream);
    hipMemsetAsync(bias2, 0, 4096, stream);   // bias2 + blw (adjacent)
    hipMemcpyAsync(bcat, b_l, 2048 * 4, hipMemcpyDeviceToDevice, stream);
    hipMemcpyAsync(bcat + 2048, b_r, 2048 * 4, hipMemcpyDeviceToDevice, stream);

    // ---- weight prep ----
    // WlT slot0, WrT slot1, WleT slot2 (one launch); WcombT occupies slot3.
    dim3 gT3(512 / 32, 2048 / 32, 3);
    transpose3_bf16<<<gT3, 256, 0, stream>>>(W_l, W_r, W_le, WlT);
    dim3 gT2(2048 / 32, 512 / 32);
    transpose_bf16<<<gT2, 256, 0, stream>>>(W_d1, Wd1T_t, 2048, 512);
    cast_bf16<<<(512 * 2048 + 255) / 256, 256, 0, stream>>>(W_l, Wlbf_t, 512 * 2048);

    // WcombT[hz*512+j, k] = sum_c W_d1[hz*512+c, j] * W_l[k, hz*512+c]
    dim3 gWc(512 / 128, 512 / 128, 4);
    mfma_gemm<__hip_bfloat16, false><<<gWc, 256, 0, stream>>>(
        Wd1T_t, 2048, 512, Wlbf_t, 2048, 512, nullptr, 0,
        WcombT, 512, (long)512 * 512, 512, 512);

    bias_acc<<<32, 256, 0, stream>>>(b_d1, conv_bias, b_l, W_d1, bias2, blw);

    // ---- counting sort of edges by dst (device-wide 3-pass scan) ----
    count_dst<<<(E + 255) / 256, 256, 0, stream>>>(ei, cnt, E);
    scan_sums<<<NB, 256, 0, stream>>>(cnt, bsum, N);
    scan_tops<<<1, 128, 0, stream>>>(bsum, NB);
    scan_final<<<NB, 256, 0, stream>>>(cnt, bsum, offs, N, E);
    fill_elist<<<(E + 255) / 256, 256, 0, stream>>>(ei, offs, cnt2, elist, ssrc, sdst, E);

    // ---- h(1) -> XL/XR ----
    encode_nodes<<<(N * 512 + 255) / 256, 256, 0, stream>>>(x, W_node, b_node, h, N);

    const int MB = MP / 128;
    dim3 gNode(2048 / 128, MB, 2);
    mfma_gemm<__hip_bfloat16, true><<<gNode, 256, 0, stream>>>(
        h, 512, 0, WlT, 512, (long)2048 * 512, bcat, 2048,
        XL, 2048, (long)MP * 2048, N, 512);

    // ---- ea (overlays h) -> edge logits ----
    encode_edges_sorted<<<(E * 512 + 255) / 256, 256, 0, stream>>>(
        edge_attr, elist, W_edge, b_edge, ea, E);

    dim3 gE(16, EP / 128);
    edge_mfma_logits<<<gE, 256, 0, stream>>>(ea, WleT, XL, XR, ssrc, sdst, att, logits, E);

    // ---- h(2) (overlays ea) -> Y = h @ WcombT (Y overlays dead XR) ----
    encode_nodes<<<(N * 512 + 255) / 256, 256, 0, stream>>>(x, W_node, b_node, h, N);

    dim3 gY(2048 / 128, MB);
    mfma_gemm<__hip_bfloat16, false><<<gY, 256, 0, stream>>>(
        h, 512, 0, WcombT, 512, 0, nullptr, 0, Y, 2048, 0, N, 512);

    gat_out<<<(N + 3) / 4, 256, 0, stream>>>(Y, ssrc, offs, logits,
                                             bias2, blw, W_d2, b_d2, out, N);
}

// Round 19
// 639.283 us; speedup vs baseline: 1.3299x; 1.0741x over previous
//
#include <hip/hip_runtime.h>
#include <hip/hip_bf16.h>

typedef __attribute__((ext_vector_type(8))) short short8;
typedef __attribute__((ext_vector_type(4))) float f32x4;
typedef unsigned int uint32;

#define GLD16(g, l) __builtin_amdgcn_global_load_lds( \
    (const __attribute__((address_space(1))) unsigned int*)(g), \
    (__attribute__((address_space(3))) unsigned int*)(l), 16, 0, 0)

__device__ __forceinline__ float bfu(unsigned short u) {
    union { uint32 v; float f; } x; x.v = ((uint32)u) << 16; return x.f;
}
__device__ __forceinline__ void storev(float* p, float v) { *p = v; }
__device__ __forceinline__ void storev(__hip_bfloat16* p, float v) { *p = __float2bfloat16(v); }

// ============ transpose fp32 [512,2048] -> bf16 [2048,512], 3 weights in z ======
__global__ __launch_bounds__(256) void transpose3_bf16(
    const float* __restrict__ W0, const float* __restrict__ W1,
    const float* __restrict__ W2, __hip_bfloat16* __restrict__ WT)
{
    __shared__ float tile[32][33];
    const float* W = (blockIdx.z == 0) ? W0 : (blockIdx.z == 1) ? W1 : W2;
    __hip_bfloat16* O = WT + (size_t)blockIdx.z * 2048 * 512;
    int k0 = blockIdx.x * 32, n0 = blockIdx.y * 32;
    int tx = threadIdx.x & 31, ty = threadIdx.x >> 5;   // 32 x 8
    #pragma unroll
    for (int i = 0; i < 32; i += 8)
        tile[ty + i][tx] = W[(size_t)(k0 + ty + i) * 2048 + n0 + tx];
    __syncthreads();
    #pragma unroll
    for (int i = 0; i < 32; i += 8)
        O[(size_t)(n0 + ty + i) * 512 + k0 + tx] = __float2bfloat16(tile[tx][ty + i]);
}

// ============ transpose fp32 [K,N] -> bf16 [N,K] (generic, for W_d1) ============
__global__ __launch_bounds__(256) void transpose_bf16(
    const float* __restrict__ W, __hip_bfloat16* __restrict__ WT, int K, int N)
{
    __shared__ float tile[32][33];
    int k0 = blockIdx.x * 32, n0 = blockIdx.y * 32;
    int tx = threadIdx.x & 31, ty = threadIdx.x >> 5;
    #pragma unroll
    for (int i = 0; i < 32; i += 8)
        tile[ty + i][tx] = W[(size_t)(k0 + ty + i) * N + n0 + tx];
    __syncthreads();
    #pragma unroll
    for (int i = 0; i < 32; i += 8)
        WT[(size_t)(n0 + ty + i) * K + k0 + tx] = __float2bfloat16(tile[tx][ty + i]);
}

__global__ __launch_bounds__(256) void cast_bf16(
    const float* __restrict__ W, __hip_bfloat16* __restrict__ O, int total)
{
    int idx = blockIdx.x * 256 + threadIdx.x;
    if (idx < total) O[idx] = __float2bfloat16(W[idx]);
}

// ============ encoders (8 cols per thread, vectorized stores) ============
__global__ __launch_bounds__(256) void encode_nodes(
    const float* __restrict__ x, const float* __restrict__ Wn,
    const float* __restrict__ bn, __hip_bfloat16* __restrict__ h, int Nn)
{
    int idx = blockIdx.x * 256 + threadIdx.x;       // one thread = 8 cols
    if (idx >= Nn * 64) return;
    int n = idx >> 6, c0 = (idx & 63) * 8;
    float xv[7];
    #pragma unroll
    for (int f = 0; f < 7; ++f) xv[f] = x[n * 7 + f];
    alignas(16) __hip_bfloat16 tmp[8];
    #pragma unroll
    for (int j = 0; j < 8; ++j) {
        int c = c0 + j;
        float acc = bn[c];
        #pragma unroll
        for (int f = 0; f < 7; ++f) acc += xv[f] * Wn[f * 512 + c];
        tmp[j] = __float2bfloat16(fmaxf(acc, 0.f));
    }
    *(uint4*)(h + (size_t)n * 512 + c0) = *(const uint4*)tmp;
}

__global__ __launch_bounds__(256) void encode_edges_sorted(
    const float* __restrict__ eat, const int* __restrict__ elist,
    const float* __restrict__ We, const float* __restrict__ be,
    __hip_bfloat16* __restrict__ ea, int E)
{
    int idx = blockIdx.x * 256 + threadIdx.x;       // one thread = 8 cols
    if (idx >= E * 64) return;
    int p = idx >> 6, c0 = (idx & 63) * 8;
    int e = elist[p];
    float e0 = eat[e * 2], e1 = eat[e * 2 + 1];
    alignas(16) __hip_bfloat16 tmp[8];
    #pragma unroll
    for (int j = 0; j < 8; ++j) {
        int c = c0 + j;
        float v = fmaf(e0, We[c], fmaf(e1, We[512 + c], be[c]));
        tmp[j] = __float2bfloat16(fmaxf(v, 0.f));
    }
    *(uint4*)(ea + (size_t)p * 512 + c0) = *(const uint4*)tmp;
}

// ============ bf16 MFMA GEMM, BK=64 ============
template <typename OutT, bool HAS_BIAS>
__global__ __launch_bounds__(256) void mfma_gemm(
    const __hip_bfloat16* __restrict__ A, int lda, long az,
    const __hip_bfloat16* __restrict__ BT, int ldb, long bz,
    const float* __restrict__ bias, long biasz,
    OutT* __restrict__ C, int ldc, long cz, int M, int K)
{
    __shared__ uint4 As4[1024];   // 16 KB
    __shared__ uint4 Bs4[1024];
    A  += (long)blockIdx.z * az;
    BT += (long)blockIdx.z * bz;
    C  += (long)blockIdx.z * cz;
    if (HAS_BIAS) bias += (long)blockIdx.z * biasz;
    const int t = threadIdx.x, lane = t & 63, w = t >> 6;
    const int wr = (w >> 1) * 64, wc = (w & 1) * 64;
    const int col0 = blockIdx.x * 128, row0 = blockIdx.y * 128;  // x = col tile (fast)
    const int lr = lane & 15, lg = lane >> 4;
    const int srow8 = lane >> 3;
    const int sch   = (lane & 7) ^ srow8;
    const int rx = lr & 7;

    const __hip_bfloat16* ApL = A + (size_t)(row0 + srow8) * lda + sch * 8;
    const __hip_bfloat16* BpL = BT + (size_t)(col0 + srow8) * ldb + sch * 8;

    f32x4 acc[4][4];
    #pragma unroll
    for (int m = 0; m < 4; ++m)
        #pragma unroll
        for (int n = 0; n < 4; ++n) acc[m][n] = 0.f;

    for (int k0 = 0; k0 < K; k0 += 64) {
        #pragma unroll
        for (int j = 0; j < 4; ++j) {
            int rb = (w + 4 * j) * 8;
            GLD16(ApL + (size_t)rb * lda + k0, As4 + (w + 4 * j) * 64);
            GLD16(BpL + (size_t)rb * ldb + k0, Bs4 + (w + 4 * j) * 64);
        }
        __syncthreads();
        #pragma unroll
        for (int kk = 0; kk < 2; ++kk) {
            short8 af[4], bfrag[4];
            #pragma unroll
            for (int m = 0; m < 4; ++m) {
                int row = wr + m * 16 + lr;
                af[m] = *(const short8*)((const char*)As4 + row * 128 + (((kk * 4 + lg) ^ rx) << 4));
            }
            #pragma unroll
            for (int n = 0; n < 4; ++n) {
                int row = wc + n * 16 + lr;
                bfrag[n] = *(const short8*)((const char*)Bs4 + row * 128 + (((kk * 4 + lg) ^ rx) << 4));
            }
            #pragma unroll
            for (int m = 0; m < 4; ++m)
                #pragma unroll
                for (int n = 0; n < 4; ++n)
                    acc[m][n] = __builtin_amdgcn_mfma_f32_16x16x32_bf16(af[m], bfrag[n], acc[m][n], 0, 0, 0);
        }
        __syncthreads();
    }

    #pragma unroll
    for (int m = 0; m < 4; ++m) {
        #pragma unroll
        for (int r = 0; r < 4; ++r) {
            int gr = row0 + wr + m * 16 + lg * 4 + r;
            if (gr >= M) continue;
            #pragma unroll
            for (int n = 0; n < 4; ++n) {
                int gc = col0 + wc + n * 16 + lr;
                float v = acc[m][n][r];
                if (HAS_BIAS) v += bias[gc];
                storev(&C[(size_t)gr * ldc + gc], v);
            }
        }
    }
}

// ============ edge GEMM (BK=64) + fused logits, sorted-edge space ============
__global__ __launch_bounds__(256) void edge_mfma_logits(
    const __hip_bfloat16* __restrict__ ea,
    const __hip_bfloat16* __restrict__ WleT,
    const __hip_bfloat16* __restrict__ XL,
    const __hip_bfloat16* __restrict__ XR,
    const int* __restrict__ ssrc,
    const int* __restrict__ sdst,
    const float* __restrict__ att,
    float* __restrict__ logits,
    int E)
{
    __shared__ uint4 As4[1024];
    __shared__ uint4 Bs4[1024];
    __shared__ int srcs[128], dsts[128];
    const int t = threadIdx.x, lane = t & 63, w = t >> 6;
    const int wr = (w >> 1) * 64, wc = (w & 1) * 64;
    const int col0 = blockIdx.x * 128, row0 = blockIdx.y * 128;
    const int lr = lane & 15, lg = lane >> 4;
    const int srow8 = lane >> 3;
    const int sch   = (lane & 7) ^ srow8;
    const int rx = lr & 7;

    if (t < 128) {
        int ge = row0 + t;
        bool ok = ge < E;
        srcs[t] = ok ? ssrc[ge] : 0;
        dsts[t] = ok ? sdst[ge] : 0;
    }
    const __hip_bfloat16* ApL = ea + (size_t)(row0 + srow8) * 512 + sch * 8;
    const __hip_bfloat16* BpL = WleT + (size_t)(col0 + srow8) * 512 + sch * 8;
    __syncthreads();

    f32x4 acc[4][4];
    #pragma unroll
    for (int m = 0; m < 4; ++m)
        #pragma unroll
        for (int n = 0; n < 4; ++n) acc[m][n] = 0.f;

    for (int k0 = 0; k0 < 512; k0 += 64) {
        #pragma unroll
        for (int j = 0; j < 4; ++j) {
            int rb = (w + 4 * j) * 8;
            GLD16(ApL + (size_t)rb * 512 + k0, As4 + (w + 4 * j) * 64);
            GLD16(BpL + (size_t)rb * 512 + k0, Bs4 + (w + 4 * j) * 64);
        }
        __syncthreads();
        #pragma unroll
        for (int kk = 0; kk < 2; ++kk) {
            short8 af[4], bfrag[4];
            #pragma unroll
            for (int m = 0; m < 4; ++m) {
                int row = wr + m * 16 + lr;
                af[m] = *(const short8*)((const char*)As4 + row * 128 + (((kk * 4 + lg) ^ rx) << 4));
            }
            #pragma unroll
            for (int n = 0; n < 4; ++n) {
                int row = wc + n * 16 + lr;
                bfrag[n] = *(const short8*)((const char*)Bs4 + row * 128 + (((kk * 4 + lg) ^ rx) << 4));
            }
            #pragma unroll
            for (int m = 0; m < 4; ++m)
                #pragma unroll
                for (int n = 0; n < 4; ++n)
                    acc[m][n] = __builtin_amdgcn_mfma_f32_16x16x32_bf16(af[m], bfrag[n], acc[m][n], 0, 0, 0);
        }
        __syncthreads();
    }

    const int hh = col0 >> 9;
    float attv[4];
    #pragma unroll
    for (int n = 0; n < 4; ++n)
        attv[n] = att[hh * 512 + ((col0 + wc + n * 16 + lr) & 511)];
    float part[4][4];
    #pragma unroll
    for (int m = 0; m < 4; ++m)
        #pragma unroll
        for (int r = 0; r < 4; ++r) part[m][r] = 0.f;

    const int prt = (lane & 3) * 8;
    const int r0e = w * 16 + (lane >> 2);
    const int s0 = srcs[r0e], s1 = srcs[r0e + 64];
    const int d0 = dsts[r0e], d1 = dsts[r0e + 64];

    #pragma unroll
    for (int pair = 0; pair < 2; ++pair) {
        #pragma unroll
        for (int sp = 0; sp < 2; ++sp) {
            int ch = pair + sp * 2;
            int cc = col0 + ch * 32;
            GLD16(XL + (size_t)s0 * 2048 + cc + prt, As4 + sp * 512 + w * 64);
            GLD16(XL + (size_t)s1 * 2048 + cc + prt, As4 + sp * 512 + (w + 4) * 64);
            GLD16(XR + (size_t)d0 * 2048 + cc + prt, Bs4 + sp * 512 + w * 64);
            GLD16(XR + (size_t)d1 * 2048 + cc + prt, Bs4 + sp * 512 + (w + 4) * 64);
        }
        __syncthreads();
        #pragma unroll
        for (int sp = 0; sp < 2; ++sp) {
            int ch = pair + sp * 2;
            const char* AsB = (const char*)(As4 + sp * 512);
            const char* BsB = (const char*)(Bs4 + sp * 512);
            #pragma unroll
            for (int n = 0; n < 4; ++n) {
                if (((wc + n * 16) >> 5) != ch) continue;
                int colin = ((n & 1) << 4) + lr;
                #pragma unroll
                for (int m = 0; m < 4; ++m) {
                    #pragma unroll
                    for (int r = 0; r < 4; ++r) {
                        int row = wr + m * 16 + lg * 4 + r;
                        float xl = bfu(*(const unsigned short*)(AsB + row * 64 + colin * 2));
                        float xr = bfu(*(const unsigned short*)(BsB + row * 64 + colin * 2));
                        float mv = acc[m][n][r] + xl + xr;
                        part[m][r] += attv[n] * ((mv > 0.f) ? mv : 0.2f * mv);
                    }
                }
            }
        }
        __syncthreads();
    }
    #pragma unroll
    for (int m = 0; m < 4; ++m) {
        #pragma unroll
        for (int r = 0; r < 4; ++r) {
            float p = part[m][r];
            p += __shfl_xor(p, 1); p += __shfl_xor(p, 2);
            p += __shfl_xor(p, 4); p += __shfl_xor(p, 8);
            int ge = row0 + wr + m * 16 + lg * 4 + r;
            if (lr == 0 && ge < E) atomicAdd(&logits[ge * 4 + hh], p);
        }
    }
}

// ============ counting sort: count + 3-pass device-wide scan + fill ============
__global__ __launch_bounds__(256) void count_dst(
    const int* __restrict__ ei, int* __restrict__ cnt, int E)
{
    int e = blockIdx.x * 256 + threadIdx.x;
    if (e < E) atomicAdd(&cnt[ei[E + e]], 1);
}

__global__ __launch_bounds__(256) void scan_sums(
    const int* __restrict__ cnt, int* __restrict__ bsum, int N)
{
    __shared__ int wsums[4];
    int t = threadIdx.x;
    int idx = blockIdx.x * 256 + t;
    int v = (idx < N) ? cnt[idx] : 0;
    #pragma unroll
    for (int o = 32; o; o >>= 1) v += __shfl_down(v, o);
    if ((t & 63) == 0) wsums[t >> 6] = v;
    __syncthreads();
    if (t == 0) bsum[blockIdx.x] = wsums[0] + wsums[1] + wsums[2] + wsums[3];
}

__global__ __launch_bounds__(128) void scan_tops(int* __restrict__ bsum, int nb)
{
    __shared__ int s0;
    int t = threadIdx.x, lane = t & 63, w = t >> 6;
    int v = (t < nb) ? bsum[t] : 0;
    int x = v;
    #pragma unroll
    for (int o = 1; o < 64; o <<= 1) {
        int y = __shfl_up(x, o);
        if (lane >= o) x += y;
    }
    if (w == 0 && lane == 63) s0 = x;
    __syncthreads();
    int ex = x - v + (w ? s0 : 0);
    if (t < nb) bsum[t] = ex;
}

__global__ __launch_bounds__(256) void scan_final(
    const int* __restrict__ cnt, const int* __restrict__ boff,
    int* __restrict__ offs, int N, int E)
{
    __shared__ int wsums[4];
    int t = threadIdx.x, lane = t & 63, w = t >> 6;
    int idx = blockIdx.x * 256 + t;
    int v = (idx < N) ? cnt[idx] : 0;
    int x = v;
    #pragma unroll
    for (int o = 1; o < 64; o <<= 1) {
        int y = __shfl_up(x, o);
        if (lane >= o) x += y;
    }
    if (lane == 63) wsums[w] = x;
    __syncthreads();
    int add = boff[blockIdx.x];
    for (int i = 0; i < w; ++i) add += wsums[i];
    if (idx < N) offs[idx] = add + x - v;
    if (blockIdx.x == 0 && t == 0) offs[N] = E;
}

__global__ __launch_bounds__(256) void fill_elist(
    const int* __restrict__ ei, const int* __restrict__ offs,
    int* __restrict__ cnt2, int* __restrict__ elist,
    int* __restrict__ ssrc, int* __restrict__ sdst, int E)
{
    int e = blockIdx.x * 256 + threadIdx.x;
    if (e >= E) return;
    int d = ei[E + e];
    int p = offs[d] + atomicAdd(&cnt2[d], 1);
    elist[p] = e;
    ssrc[p] = ei[e];
    sdst[p] = d;
}

// ============ bias prep ============
__global__ __launch_bounds__(256) void bias_acc(
    const float* __restrict__ bd1, const float* __restrict__ cb,
    const float* __restrict__ bl, const float* __restrict__ Wd1,
    float* __restrict__ bias2, float* __restrict__ blw)
{
    int g = blockIdx.x * 256 + threadIdx.x;   // 8192 threads: 512 j x 16 slices
    int j = g & 511, slice = g >> 9;
    float pa = (slice == 0) ? bd1[j] : 0.f, pb = 0.f;
    for (int k = slice * 128; k < slice * 128 + 128; ++k) {
        float wv = Wd1[(size_t)k * 512 + j];
        pa += cb[k] * wv;
        pb += bl[k] * wv;
    }
    atomicAdd(&bias2[j], pa);
    atomicAdd(&blw[j], pb);
}

// ============ fused output (single-pass softmax: acc unnormalized, scale last) ==
__global__ __launch_bounds__(256) void gat_out(
    const __hip_bfloat16* __restrict__ Y,     // [N,4,512] bf16 (no bias terms)
    const int* __restrict__ ssrc, const int* __restrict__ offs,
    const float* __restrict__ logits,         // [E,4] sorted
    const float* __restrict__ bias2, const float* __restrict__ blw,
    const float* __restrict__ Wd2,
    const float* __restrict__ bd2,
    float* __restrict__ out, int N)
{
    __shared__ float wds[512 * 6];
    int t = threadIdx.x;
    for (int i = t; i < 512 * 6; i += 256) wds[i] = Wd2[i];
    __syncthreads();
    int w = t >> 6, lane = t & 63;
    int dst = blockIdx.x * 4 + w;
    if (dst >= N) return;
    int s = offs[dst], cntE = offs[dst + 1] - s;

    // single pass: acc_h = sum e^l * Y[src,h]; den_h = sum e^l; out uses acc/den
    float den[4] = {0.f, 0.f, 0.f, 0.f};
    float acc[4][8] = {};
    for (int i = 0; i < cntE; ++i) {
        int p = s + i;
        int src = ssrc[p];
        #pragma unroll
        for (int h = 0; h < 4; ++h) {
            float ex = expf(logits[p * 4 + h]);   // shift-invariant; logits O(0.1)
            den[h] += ex;
            uint4 q = *(const uint4*)((const unsigned short*)Y
                        + ((size_t)src * 4 + h) * 512 + lane * 8);
            acc[h][0] += ex * bfu((unsigned short)(q.x & 0xffff));
            acc[h][1] += ex * bfu((unsigned short)(q.x >> 16));
            acc[h][2] += ex * bfu((unsigned short)(q.y & 0xffff));
            acc[h][3] += ex * bfu((unsigned short)(q.y >> 16));
            acc[h][4] += ex * bfu((unsigned short)(q.z & 0xffff));
            acc[h][5] += ex * bfu((unsigned short)(q.z >> 16));
            acc[h][6] += ex * bfu((unsigned short)(q.w & 0xffff));
            acc[h][7] += ex * bfu((unsigned short)(q.w >> 16));
        }
    }
    float inv[4];
    #pragma unroll
    for (int h = 0; h < 4; ++h) inv[h] = 1.f / (den[h] + 1e-16f);

    float gate = (cntE > 0) ? 1.f : 0.f;
    float p6[6] = {0.f, 0.f, 0.f, 0.f, 0.f, 0.f};
    // channel c = h*512 + lane*8 + j maps to acc[h][j]; here h spans via lane? No:
    // each lane covers cols lane*8..lane*8+7 within EACH head block (4 heads).
    #pragma unroll
    for (int h = 0; h < 4; ++h) {
        #pragma unroll
        for (int j = 0; j < 8; ++j) {
            int c = h * 512 + lane * 8 + j;
            // Y holds per-head halves of the 2048-dim; but bias2/blw/Wd2 are 512-dim
            // (decoder input). Y was already multiplied by Wcomb per head, so the
            // four heads' contributions SUM into the same 512 channels:
            (void)c;
        }
    }
    // sum heads first (Wcomb outputs share the 512-dim space), then decode
    float zsum[8];
    #pragma unroll
    for (int j = 0; j < 8; ++j)
        zsum[j] = acc[0][j] * inv[0] + acc[1][j] * inv[1]
                + acc[2][j] * inv[2] + acc[3][j] * inv[3];
    #pragma unroll
    for (int j = 0; j < 8; ++j) {
        int c = lane * 8 + j;
        float u = fmaxf(zsum[j] + bias2[c] + gate * blw[c], 0.f);
        #pragma unroll
        for (int jj = 0; jj < 6; ++jj) p6[jj] += u * wds[c * 6 + jj];
    }
    #pragma unroll
    for (int off = 32; off; off >>= 1)
        #pragma unroll
        for (int jj = 0; jj < 6; ++jj) p6[jj] += __shfl_down(p6[jj], off);
    if (lane == 0) {
        #pragma unroll
        for (int jj = 0; jj < 6; ++jj)
            out[(size_t)dst * 6 + jj] = 1.f / (1.f + expf(-(p6[jj] + bd2[jj])));
    }
}

extern "C" void kernel_launch(void* const* d_in, const int* in_sizes, int n_in,
                              void* d_out, int out_size, void* d_ws, size_t ws_size,
                              hipStream_t stream)
{
    const float* x         = (const float*)d_in[0];
    const float* edge_attr = (const float*)d_in[1];
    const int*   ei        = (const int*)d_in[2];
    const float* W_node = (const float*)d_in[3],  *b_node = (const float*)d_in[4];
    const float* W_edge = (const float*)d_in[5],  *b_edge = (const float*)d_in[6];
    const float* W_l    = (const float*)d_in[7],  *b_l    = (const float*)d_in[8];
    const float* W_r    = (const float*)d_in[9],  *b_r    = (const float*)d_in[10];
    const float* W_le   = (const float*)d_in[11];
    const float* att    = (const float*)d_in[12];
    const float* conv_bias = (const float*)d_in[13];
    const float* W_d1   = (const float*)d_in[14], *b_d1 = (const float*)d_in[15];
    const float* W_d2   = (const float*)d_in[16], *b_d2 = (const float*)d_in[17];
    float* out = (float*)d_out;

    const int N = in_sizes[0] / 7;   // 25000
    const int E = in_sizes[1] / 2;   // 50000
    const int MP = (N + 127) & ~127;
    const int EP = (E + 127) & ~127;
    const int NB = (N + 255) / 256;

    // ---- workspace layout (~268 MB) ----
    char* ws = (char*)d_ws;
    const size_t szR0 = (size_t)EP * 512 * 2;
    const size_t szX  = (size_t)MP * 2048 * 2;
    const size_t szW  = (size_t)2048 * 512 * 2;
    const size_t szlg = (size_t)E * 4 * 4;
    const size_t szI  = (((size_t)(N + 1) * 4) + 15) & ~(size_t)15;
    const size_t o_XL = szR0;
    const size_t o_XR = o_XL + szX;
    const size_t o_W  = o_XR + szX;
    const size_t o_lg = o_W + 4 * szW;
    const size_t o_b2 = o_lg + szlg;
    const size_t o_blw = o_b2 + 2048;
    const size_t o_bc = o_blw + 2048;
    const size_t o_cnt = o_bc + 4096 * 4;
    const size_t o_cnt2 = o_cnt + szI;
    const size_t o_off = o_cnt2 + szI;
    const size_t o_el = o_off + szI;
    const size_t o_ss = o_el + (size_t)E * 4;
    const size_t o_sd = o_ss + (size_t)E * 4;
    const size_t o_bs = o_sd + (size_t)E * 4;
    const size_t need = o_bs + 512;
    if (ws_size < need) return;

    __hip_bfloat16* h   = (__hip_bfloat16*)ws;
    __hip_bfloat16* ea  = (__hip_bfloat16*)ws;
    __hip_bfloat16* XL  = (__hip_bfloat16*)(ws + o_XL);
    __hip_bfloat16* XR  = (__hip_bfloat16*)(ws + o_XR);
    __hip_bfloat16* Y   = XR;
    __hip_bfloat16* WlT = (__hip_bfloat16*)(ws + o_W);
    __hip_bfloat16* WleT= WlT + szW;
    __hip_bfloat16* WcombT = (__hip_bfloat16*)(ws + o_W) + 3 * (szW / 2);
    __hip_bfloat16* Wd1T_t = (__hip_bfloat16*)(ws + o_XL);
    __hip_bfloat16* Wlbf_t = (__hip_bfloat16*)(ws + o_XL + szW);
    float* logits = (float*)(ws + o_lg);
    float* bias2  = (float*)(ws + o_b2);
    float* blw    = (float*)(ws + o_blw);
    float* bcat   = (float*)(ws + o_bc);
    int* cnt   = (int*)(ws + o_cnt);
    int* cnt2  = (int*)(ws + o_cnt2);
    int* offs  = (int*)(ws + o_off);
    int* elist = (int*)(ws + o_el);
    int* ssrc  = (int*)(ws + o_ss);
    int* sdst  = (int*)(ws + o_sd);
    int* bsum  = (int*)(ws + o_bs);

    hipMemsetAsync(logits, 0, szlg, stream);
    hipMemsetAsync(cnt, 0, szI, stream);
    hipMemsetAsync(cnt2, 0, szI, stream);
    hipMemsetAsync(bias2, 0, 4096, stream);
    hipMemcpyAsync(bcat, b_l, 2048 * 4, hipMemcpyDeviceToDevice, stream);
    hipMemcpyAsync(bcat + 2048, b_r, 2048 * 4, hipMemcpyDeviceToDevice, stream);

    dim3 gT3(512 / 32, 2048 / 32, 3);
    transpose3_bf16<<<gT3, 256, 0, stream>>>(W_l, W_r, W_le, WlT);
    dim3 gT2(2048 / 32, 512 / 32);
    transpose_bf16<<<gT2, 256, 0, stream>>>(W_d1, Wd1T_t, 2048, 512);
    cast_bf16<<<(512 * 2048 + 255) / 256, 256, 0, stream>>>(W_l, Wlbf_t, 512 * 2048);

    dim3 gWc(512 / 128, 512 / 128, 4);
    mfma_gemm<__hip_bfloat16, false><<<gWc, 256, 0, stream>>>(
        Wd1T_t, 2048, 512, Wlbf_t, 2048, 512, nullptr, 0,
        WcombT, 512, (long)512 * 512, 512, 512);

    bias_acc<<<32, 256, 0, stream>>>(b_d1, conv_bias, b_l, W_d1, bias2, blw);

    count_dst<<<(E + 255) / 256, 256, 0, stream>>>(ei, cnt, E);
    scan_sums<<<NB, 256, 0, stream>>>(cnt, bsum, N);
    scan_tops<<<1, 128, 0, stream>>>(bsum, NB);
    scan_final<<<NB, 256, 0, stream>>>(cnt, bsum, offs, N, E);
    fill_elist<<<(E + 255) / 256, 256, 0, stream>>>(ei, offs, cnt2, elist, ssrc, sdst, E);

    encode_nodes<<<(N * 64 + 255) / 256, 256, 0, stream>>>(x, W_node, b_node, h, N);

    const int MB = MP / 128;
    dim3 gNode(2048 / 128, MB, 2);
    mfma_gemm<__hip_bfloat16, true><<<gNode, 256, 0, stream>>>(
        h, 512, 0, WlT, 512, (long)2048 * 512, bcat, 2048,
        XL, 2048, (long)MP * 2048, N, 512);

    encode_edges_sorted<<<(E * 64 + 255) / 256, 256, 0, stream>>>(
        edge_attr, elist, W_edge, b_edge, ea, E);

    dim3 gE(16, EP / 128);
    edge_mfma_logits<<<gE, 256, 0, stream>>>(ea, WleT, XL, XR, ssrc, sdst, att, logits, E);

    encode_nodes<<<(N * 64 + 255) / 256, 256, 0, stream>>>(x, W_node, b_node, h, N);

    dim3 gY(2048 / 128, MB);
    mfma_gemm<__hip_bfloat16, false><<<gY, 256, 0, stream>>>(
        h, 512, 0, WcombT, 512, 0, nullptr, 0, Y, 2048, 0, N, 512);

    gat_out<<<(N + 3) / 4, 256, 0, stream>>>(Y, ssrc, offs, logits,
                                             bias2, blw, W_d2, b_d2, out, N);
}